// Round 9
// baseline (1034.626 us; speedup 1.0000x reference)
//
#include <hip/hip_runtime.h>
#include <hip/hip_bf16.h>

#define N_NODES 20000
#define N_EDGES 100000
#define ET (N_EDGES + N_NODES)   // 120000 incl. self-loops
#define G_GRAPHS 16
#define SLOPE 0.2f

using short8  = __attribute__((ext_vector_type(8))) short;
using floatx4 = __attribute__((ext_vector_type(4))) float;

__device__ __forceinline__ float lrelu(float x) { return x > 0.f ? x : SLOPE * x; }

__device__ __forceinline__ float b2f(unsigned short u) {
    union { unsigned int i; float f; } v; v.i = ((unsigned int)u) << 16; return v.f;
}
__device__ __forceinline__ unsigned short f2b(float f) {
    union { float f; unsigned int i; } v; v.f = f;
    unsigned int i = v.i;
    return (unsigned short)((i + 0x7fffu + ((i >> 16) & 1u)) >> 16);  // RNE
}

__device__ __forceinline__ void gld16(const void* g, void* l) {
    __builtin_amdgcn_global_load_lds((const __attribute__((address_space(1))) void*)g,
                                     (__attribute__((address_space(3))) void*)l, 16, 0, 0);
}

__device__ int dev_lower_bound(const int* a, int n, int key) {
    int lo = 0, hi = n;
    while (lo < hi) { int mid = (lo + hi) >> 1; if (a[mid] < key) lo = mid + 1; else hi = mid; }
    return lo;
}

__global__ void zero_kernel(int* __restrict__ p, int n) {
    int i = blockIdx.x * blockDim.x + threadIdx.x;
    if (i < n) p[i] = 0;
}

// ---------------- CSR build (by dst) ----------------
__global__ void count_kernel(const int* __restrict__ ei, int* __restrict__ counts) {
    int e = blockIdx.x * blockDim.x + threadIdx.x;
    if (e >= ET) return;
    int dst = (e < N_EDGES) ? ei[N_EDGES + e] : (e - N_EDGES);
    atomicAdd(&counts[dst], 1);
}

// scan also re-zeroes counts so fill can reuse it as a cursor (saves one launch)
__global__ void scan_kernel(int* __restrict__ counts, int* __restrict__ row_ptr) {
    __shared__ int sums[256];
    int t = threadIdx.x;
    const int CH = (N_NODES + 255) / 256;
    int base = t * CH;
    int s = 0;
    for (int i = 0; i < CH; i++) { int idx = base + i; if (idx < N_NODES) s += counts[idx]; }
    sums[t] = s;
    __syncthreads();
    for (int off = 1; off < 256; off <<= 1) {
        int v = (t >= off) ? sums[t - off] : 0;
        __syncthreads();
        sums[t] += v;
        __syncthreads();
    }
    int run = (t == 0) ? 0 : sums[t - 1];
    for (int i = 0; i < CH; i++) {
        int idx = base + i;
        if (idx < N_NODES) {
            int c = counts[idx];
            row_ptr[idx] = run;
            run += c;
            counts[idx] = 0;
        }
    }
    if (t == 255) row_ptr[N_NODES] = run;
}

__global__ void fill_kernel(const int* __restrict__ ei, const int* __restrict__ row_ptr,
                            int* __restrict__ fill_cnt, int* __restrict__ col) {
    int e = blockIdx.x * blockDim.x + threadIdx.x;
    if (e >= ET) return;
    int src, dst;
    if (e < N_EDGES) { src = ei[e]; dst = ei[N_EDGES + e]; }
    else             { src = dst = e - N_EDGES; }
    int pos = atomicAdd(&fill_cnt[dst], 1);
    col[row_ptr[dst] + pos] = src;
}

// ---------------- prep megakernel: 3 weight transposes (z=0..2) + wes fold (z=3) ----------
__global__ void prep_kernel(const float* __restrict__ W1, const float* __restrict__ W2,
                            const float* __restrict__ W3, const float* __restrict__ a1s,
                            const float* __restrict__ a1d, unsigned short* __restrict__ W1t,
                            unsigned short* __restrict__ W2t, unsigned short* __restrict__ W3t,
                            float* __restrict__ w_es, float* __restrict__ w_ed) {
    int z = blockIdx.z;
    if (z == 3) {   // fold a1s/a1d into W1: w_es[k][hd] = <W1[k, hd*256:...], a1s[hd]>
        if (blockIdx.x >= 8 || blockIdx.y > 0 || threadIdx.x >= 128) return;
        int hd = blockIdx.x, k = threadIdx.x;
        const float* w   = W1 + (size_t)k * 2048 + hd * 256;
        const float* as_ = a1s + hd * 256;
        const float* ad_ = a1d + hd * 256;
        float s1 = 0.f, s2 = 0.f;
        for (int c = 0; c < 256; c++) { float wv = w[c]; s1 += wv * as_[c]; s2 += wv * ad_[c]; }
        w_es[k * 8 + hd] = s1;
        w_ed[k * 8 + hd] = s2;
        return;
    }
    const float* W; unsigned short* Wt; int K, N;
    if (z == 0)      { W = W1; Wt = W1t; K = 128;  N = 2048; }
    else if (z == 1) { W = W2; Wt = W2t; K = 2048; N = 2048; }
    else             { W = W3; Wt = W3t; K = 2048; N = 512;  }
    int bn = blockIdx.x * 32, bk = blockIdx.y * 32;
    if (bn >= N || bk >= K) return;
    __shared__ float tile[32][33];
    int tx = threadIdx.x & 31, ty = threadIdx.x >> 5;
#pragma unroll
    for (int p = 0; p < 32; p += 8)
        tile[ty + p][tx] = W[(size_t)(bk + ty + p) * N + bn + tx];
    __syncthreads();
#pragma unroll
    for (int p = 0; p < 32; p += 8)
        Wt[(size_t)(bn + ty + p) * K + bk + tx] = f2b(tile[tx][ty + p]);
}

// ---------------- GEMM0 + layer-1 logits fused ----------------
// h0 = lrelu(x@W0+b0); es/ed[n,hd] = <h0row, w_es/w_ed[:,hd]> via per-wave shuffle reduce.
__global__ void gemm0es_kernel(const float* __restrict__ x, const float* __restrict__ W0,
                               const float* __restrict__ b0, const float* __restrict__ w_es,
                               const float* __restrict__ w_ed, unsigned short* __restrict__ h0,
                               float* __restrict__ es, float* __restrict__ ed) {
    __shared__ float xr[32];
    __shared__ float red[2][16];
    int n = blockIdx.x, t = threadIdx.x;  // 128 threads = 2 waves
    if (t < 32) xr[t] = x[n * 32 + t];
    __syncthreads();
    float acc = 0.f;
#pragma unroll
    for (int k = 0; k < 32; k++) acc += xr[k] * W0[k * 128 + t];
    float h = lrelu(acc + b0[t]);
    h0[(size_t)n * 128 + t] = f2b(h);
    float p[16];
#pragma unroll
    for (int hd = 0; hd < 8; hd++) {
        p[hd]     = h * w_es[t * 8 + hd];
        p[8 + hd] = h * w_ed[t * 8 + hd];
    }
#pragma unroll
    for (int m = 1; m < 64; m <<= 1)
#pragma unroll
        for (int i = 0; i < 16; i++) p[i] += __shfl_xor(p[i], m);
    int w = t >> 6, l = t & 63;
    if (l == 0)
#pragma unroll
        for (int i = 0; i < 16; i++) red[w][i] = p[i];
    __syncthreads();
    if (t < 8)       es[n * 8 + t] = red[0][t] + red[1][t];
    else if (t < 16) ed[n * 8 + (t - 8)] = red[0][t] + red[1][t];
}

// ---------------- layer-1 aggregation over 128-dim input ----------------
__global__ __launch_bounds__(256) void agg1_wave(const unsigned short* __restrict__ h0,
                                                 const float* __restrict__ es,
                                                 const float* __restrict__ ed,
                                                 const int* __restrict__ row_ptr,
                                                 const int* __restrict__ col,
                                                 unsigned short* __restrict__ outp) {
    int wv = threadIdx.x >> 6, l = threadIdx.x & 63;
    int v = blockIdx.x * 4 + wv;
    if (v >= N_NODES) return;
    int rs = row_ptr[v], deg = row_ptr[v + 1] - rs;
    float edv[8], den[8], a0[8], a1[8];
#pragma unroll
    for (int hd = 0; hd < 8; hd++) { edv[hd] = ed[v * 8 + hd]; den[hd] = 0.f; a0[hd] = 0.f; a1[hd] = 0.f; }
    int sN = (deg > 0) ? col[rs] : 0;
    for (int e = 0; e < deg; e++) {
        int s = sN;
        if (e + 1 < deg) sN = col[rs + e + 1];
        unsigned int u = *(const unsigned int*)&h0[(size_t)s * 128 + l * 2];
        float x0 = b2f((unsigned short)(u & 0xffff)), x1 = b2f((unsigned short)(u >> 16));
#pragma unroll
        for (int hd = 0; hd < 8; hd++) {
            float a = __expf(lrelu(es[s * 8 + hd] + edv[hd]));
            den[hd] += a;
            a0[hd] += a * x0;
            a1[hd] += a * x1;
        }
    }
#pragma unroll
    for (int hd = 0; hd < 8; hd++) {
        float inv = 1.f / (den[hd] + 1e-16f);
        unsigned int o = (unsigned int)f2b(a0[hd] * inv) | ((unsigned int)f2b(a1[hd] * inv) << 16);
        *(unsigned int*)&outp[(size_t)v * 1024 + hd * 128 + l * 2] = o;
    }
}

// ---------------- MFMA GEMM, BK=64: C[M,N] bf16 = A[M,K] @ Bt[N,K] ----------------
// 128x128 tile, BK=64 (32 MFMA per barrier pair, halved barrier count vs BK=32).
// LDS 32 KB. Colblock swizzle: physical = logical ^ (row & 7) -> uniform 8-lane/group
// spread on ds_read_b128. Operands swapped (mfma(b,a)) -> ushort4 C stores.
__global__ __launch_bounds__(256) void gemm_mfma(const unsigned short* __restrict__ A,
                                                 const unsigned short* __restrict__ Bt,
                                                 unsigned short* __restrict__ C,
                                                 int M, int N, int K) {
    __shared__ __align__(16) unsigned short As[128][64];
    __shared__ __align__(16) unsigned short Bs[128][64];
    int t = threadIdx.x;
    int w = t >> 6, l = t & 63;
    int r0 = blockIdx.y * 128, c0 = blockIdx.x * 128;
    int wr = (w >> 1) * 64, wc = (w & 1) * 64;
    int srow = l >> 3;                          // 0..7: staging row within 8-row group
    int gcb  = (l & 7) ^ srow;                  // swizzled global colblock (row&7 == srow)
    int m16 = l & 15, qb = l >> 4;
    floatx4 acc[4][4] = {};

    for (int k0 = 0; k0 < K; k0 += 64) {
        __syncthreads();
#pragma unroll
        for (int q = 0; q < 4; q++) {
            int row = w * 32 + q * 8 + srow;
            int ga = min(r0 + row, M - 1);
            gld16(A + (size_t)ga * K + k0 + gcb * 8, &As[w * 32 + q * 8][0]);
            gld16(Bt + (size_t)(c0 + row) * K + k0 + gcb * 8, &Bs[w * 32 + q * 8][0]);
        }
        __syncthreads();
#pragma unroll
        for (int kh = 0; kh < 2; kh++) {
            int roff = (((kh * 4 + qb) ^ (m16 & 7)) * 8);
            short8 af[4], bfr[4];
#pragma unroll
            for (int i = 0; i < 4; i++) af[i] = *(const short8*)&As[wr + i * 16 + m16][roff];
#pragma unroll
            for (int j = 0; j < 4; j++) bfr[j] = *(const short8*)&Bs[wc + j * 16 + m16][roff];
#pragma unroll
            for (int i = 0; i < 4; i++)
#pragma unroll
                for (int j = 0; j < 4; j++)
                    acc[i][j] = __builtin_amdgcn_mfma_f32_16x16x32_bf16(bfr[j], af[i], acc[i][j], 0, 0, 0);
        }
    }
    int quad = l >> 4;
#pragma unroll
    for (int i = 0; i < 4; i++) {
        int r = r0 + wr + i * 16 + m16;
        if (r < M) {
#pragma unroll
            for (int j = 0; j < 4; j++) {
                int c = c0 + wc + j * 16 + quad * 4;
                ushort4 o = make_ushort4(f2b(acc[i][j][0]), f2b(acc[i][j][1]),
                                         f2b(acc[i][j][2]), f2b(acc[i][j][3]));
                *(ushort4*)&C[(size_t)r * N + c] = o;
            }
        }
    }
}

// ---------------- layer-1 per-head GEMM (BK=64): C[M,2048] = A_head[M,128]@W1t + b1, lrelu --
__global__ __launch_bounds__(256) void gemm_mfma_h1(const unsigned short* __restrict__ A,
                                                    const unsigned short* __restrict__ Bt,
                                                    const float* __restrict__ bias,
                                                    unsigned short* __restrict__ C,
                                                    int M) {
    const int N = 2048, K = 128;
    __shared__ __align__(16) unsigned short As[128][64];
    __shared__ __align__(16) unsigned short Bs[128][64];
    int t = threadIdx.x;
    int w = t >> 6, l = t & 63;
    int r0 = blockIdx.y * 128, c0 = blockIdx.x * 128;
    int wr = (w >> 1) * 64, wc = (w & 1) * 64;
    int srow = l >> 3;
    int gcb  = (l & 7) ^ srow;
    int m16 = l & 15, qb = l >> 4;
    int aoff = (c0 >> 8) * 128;                 // head * 128
    floatx4 acc[4][4] = {};

    for (int k0 = 0; k0 < K; k0 += 64) {
        __syncthreads();
#pragma unroll
        for (int q = 0; q < 4; q++) {
            int row = w * 32 + q * 8 + srow;
            int ga = min(r0 + row, M - 1);
            gld16(A + (size_t)ga * 1024 + aoff + k0 + gcb * 8, &As[w * 32 + q * 8][0]);
            gld16(Bt + (size_t)(c0 + row) * K + k0 + gcb * 8, &Bs[w * 32 + q * 8][0]);
        }
        __syncthreads();
#pragma unroll
        for (int kh = 0; kh < 2; kh++) {
            int roff = (((kh * 4 + qb) ^ (m16 & 7)) * 8);
            short8 af[4], bfr[4];
#pragma unroll
            for (int i = 0; i < 4; i++) af[i] = *(const short8*)&As[wr + i * 16 + m16][roff];
#pragma unroll
            for (int j = 0; j < 4; j++) bfr[j] = *(const short8*)&Bs[wc + j * 16 + m16][roff];
#pragma unroll
            for (int i = 0; i < 4; i++)
#pragma unroll
                for (int j = 0; j < 4; j++)
                    acc[i][j] = __builtin_amdgcn_mfma_f32_16x16x32_bf16(bfr[j], af[i], acc[i][j], 0, 0, 0);
        }
    }
    int quad = l >> 4;
#pragma unroll
    for (int i = 0; i < 4; i++) {
        int r = r0 + wr + i * 16 + m16;
        if (r < M) {
#pragma unroll
            for (int j = 0; j < 4; j++) {
                int c = c0 + wc + j * 16 + quad * 4;
                ushort4 o = make_ushort4(f2b(lrelu(acc[i][j][0] + bias[c + 0])),
                                         f2b(lrelu(acc[i][j][1] + bias[c + 1])),
                                         f2b(lrelu(acc[i][j][2] + bias[c + 2])),
                                         f2b(lrelu(acc[i][j][3] + bias[c + 3])));
                *(ushort4*)&C[(size_t)r * N + c] = o;
            }
        }
    }
}

// ---------------- attention logits (layers 2,3) ----------------
__global__ void att8_kernel(const unsigned short* __restrict__ h, const float* __restrict__ a_s,
                            const float* __restrict__ a_d, float* __restrict__ es,
                            float* __restrict__ ed) {
    int n = blockIdx.x, t = threadIdx.x;  // 256 = 8 heads x 32 lanes
    int hd = t >> 5, l = t & 31;
    const unsigned short* hr = h + (size_t)n * 2048 + hd * 256 + l * 8;
    const float* as_ = a_s + hd * 256 + l * 8;
    const float* ad_ = a_d + hd * 256 + l * 8;
    uint4 u = *(const uint4*)hr;
    float v[8] = { b2f((unsigned short)(u.x & 0xffff)), b2f((unsigned short)(u.x >> 16)),
                   b2f((unsigned short)(u.y & 0xffff)), b2f((unsigned short)(u.y >> 16)),
                   b2f((unsigned short)(u.z & 0xffff)), b2f((unsigned short)(u.z >> 16)),
                   b2f((unsigned short)(u.w & 0xffff)), b2f((unsigned short)(u.w >> 16)) };
    float s1 = 0.f, s2 = 0.f;
#pragma unroll
    for (int j = 0; j < 8; j++) { s1 += v[j] * as_[j]; s2 += v[j] * ad_[j]; }
    for (int m = 16; m >= 1; m >>= 1) { s1 += __shfl_xor(s1, m); s2 += __shfl_xor(s2, m); }
    if (l == 0) { es[n * 8 + hd] = s1; ed[n * 8 + hd] = s2; }
}

__global__ void att1_kernel(const unsigned short* __restrict__ h, const float* __restrict__ a_s,
                            const float* __restrict__ a_d, float* __restrict__ es,
                            float* __restrict__ ed) {
    int n = blockIdx.x, l = threadIdx.x;  // 64 threads
    const unsigned short* hr = h + (size_t)n * 512 + l * 8;
    const float* as_ = a_s + l * 8;
    const float* ad_ = a_d + l * 8;
    uint4 u = *(const uint4*)hr;
    float v[8] = { b2f((unsigned short)(u.x & 0xffff)), b2f((unsigned short)(u.x >> 16)),
                   b2f((unsigned short)(u.y & 0xffff)), b2f((unsigned short)(u.y >> 16)),
                   b2f((unsigned short)(u.z & 0xffff)), b2f((unsigned short)(u.z >> 16)),
                   b2f((unsigned short)(u.w & 0xffff)), b2f((unsigned short)(u.w >> 16)) };
    float s1 = 0.f, s2 = 0.f;
#pragma unroll
    for (int j = 0; j < 8; j++) { s1 += v[j] * as_[j]; s2 += v[j] * ad_[j]; }
    for (int m = 32; m >= 1; m >>= 1) { s1 += __shfl_xor(s1, m); s2 += __shfl_xor(s2, m); }
    if (l == 0) { es[n] = s1; ed[n] = s2; }
}

// ---------------- wave-per-dst GAT aggregation, edge-unrolled x2 ----------------
template <int H, int C>
__global__ __launch_bounds__(256) void agg_wave(const unsigned short* __restrict__ hmid,
                                                const float* __restrict__ es,
                                                const float* __restrict__ ed,
                                                const int* __restrict__ row_ptr,
                                                const int* __restrict__ col,
                                                const float* __restrict__ bias,
                                                unsigned short* __restrict__ out) {
    constexpr int HC = H * C;
    constexpr int CH = HC / 512;            // uint4 chunks per lane: 4 (2048) or 1 (512)
    int wv = threadIdx.x >> 6, l = threadIdx.x & 63;
    int v = blockIdx.x * 4 + wv;
    if (v >= N_NODES) return;
    int rs = row_ptr[v], deg = row_ptr[v + 1] - rs;
    int hd[CH];
    float edv[CH], den[CH], acc[CH][8];
#pragma unroll
    for (int c = 0; c < CH; c++) {
        hd[c] = (c * 512 + l * 8) / C;
        edv[c] = ed[v * H + hd[c]];
        den[c] = 0.f;
#pragma unroll
        for (int k = 0; k < 8; k++) acc[c][k] = 0.f;
    }
    int e = 0;
    for (; e + 2 <= deg; e += 2) {          // two independent gather chains in flight
        int s0 = col[rs + e], s1 = col[rs + e + 1];
        const unsigned short* hr0 = hmid + (size_t)s0 * HC + l * 8;
        const unsigned short* hr1 = hmid + (size_t)s1 * HC + l * 8;
        uint4 u0[CH], u1[CH];
#pragma unroll
        for (int c = 0; c < CH; c++) { u0[c] = *(const uint4*)(hr0 + c * 512); u1[c] = *(const uint4*)(hr1 + c * 512); }
        float ex0[CH], ex1[CH];
#pragma unroll
        for (int c = 0; c < CH; c++) {
            ex0[c] = __expf(lrelu(es[s0 * H + hd[c]] + edv[c]));
            ex1[c] = __expf(lrelu(es[s1 * H + hd[c]] + edv[c]));
            den[c] += ex0[c] + ex1[c];
        }
#pragma unroll
        for (int c = 0; c < CH; c++) {
            float a = ex0[c], b = ex1[c];
            acc[c][0] += a * b2f((unsigned short)(u0[c].x & 0xffff)) + b * b2f((unsigned short)(u1[c].x & 0xffff));
            acc[c][1] += a * b2f((unsigned short)(u0[c].x >> 16))    + b * b2f((unsigned short)(u1[c].x >> 16));
            acc[c][2] += a * b2f((unsigned short)(u0[c].y & 0xffff)) + b * b2f((unsigned short)(u1[c].y & 0xffff));
            acc[c][3] += a * b2f((unsigned short)(u0[c].y >> 16))    + b * b2f((unsigned short)(u1[c].y >> 16));
            acc[c][4] += a * b2f((unsigned short)(u0[c].z & 0xffff)) + b * b2f((unsigned short)(u1[c].z & 0xffff));
            acc[c][5] += a * b2f((unsigned short)(u0[c].z >> 16))    + b * b2f((unsigned short)(u1[c].z >> 16));
            acc[c][6] += a * b2f((unsigned short)(u0[c].w & 0xffff)) + b * b2f((unsigned short)(u1[c].w & 0xffff));
            acc[c][7] += a * b2f((unsigned short)(u0[c].w >> 16))    + b * b2f((unsigned short)(u1[c].w >> 16));
        }
    }
    if (e < deg) {
        int s = col[rs + e];
        const unsigned short* hr = hmid + (size_t)s * HC + l * 8;
#pragma unroll
        for (int c = 0; c < CH; c++) {
            uint4 u = *(const uint4*)(hr + c * 512);
            float a = __expf(lrelu(es[s * H + hd[c]] + edv[c]));
            den[c] += a;
            acc[c][0] += a * b2f((unsigned short)(u.x & 0xffff));
            acc[c][1] += a * b2f((unsigned short)(u.x >> 16));
            acc[c][2] += a * b2f((unsigned short)(u.y & 0xffff));
            acc[c][3] += a * b2f((unsigned short)(u.y >> 16));
            acc[c][4] += a * b2f((unsigned short)(u.z & 0xffff));
            acc[c][5] += a * b2f((unsigned short)(u.z >> 16));
            acc[c][6] += a * b2f((unsigned short)(u.w & 0xffff));
            acc[c][7] += a * b2f((unsigned short)(u.w >> 16));
        }
    }
#pragma unroll
    for (int c = 0; c < CH; c++) {
        float inv = 1.f / (den[c] + 1e-16f);
        unsigned short o[8];
#pragma unroll
        for (int k = 0; k < 8; k++)
            o[k] = f2b(lrelu(acc[c][k] * inv + bias[c * 512 + l * 8 + k]));
        *(uint4*)&out[(size_t)v * HC + c * 512 + l * 8] = *(const uint4*)o;
    }
}

// ---------------- fused mean-pool + final linear: one block per graph ----------------
__global__ __launch_bounds__(512) void poolfinal_kernel(const unsigned short* __restrict__ h3,
                                                        const int* __restrict__ batch,
                                                        const float* __restrict__ Wf,
                                                        const float* __restrict__ bf,
                                                        float* __restrict__ out) {
    int g = blockIdx.x, t = threadIdx.x;  // 512 threads, one output col each
    __shared__ float mr[512];
    int st = dev_lower_bound(batch, N_NODES, g);
    int en = dev_lower_bound(batch, N_NODES, g + 1);
    float s = 0.f;
    for (int n = st; n < en; n++) s += b2f(h3[(size_t)n * 512 + t]);
    mr[t] = s * (1.f / fmaxf((float)(en - st), 1.f));
    __syncthreads();
    float o = 0.f;
    for (int k = 0; k < 512; k++) o += mr[k] * Wf[k * 512 + t];
    out[g * 512 + t] = lrelu(o + bf[t]);
}

extern "C" void kernel_launch(void* const* d_in, const int* in_sizes, int n_in,
                              void* d_out, int out_size, void* d_ws, size_t ws_size,
                              hipStream_t stream) {
    const float* x   = (const float*)d_in[0];
    const int*   ei  = (const int*)d_in[1];
    const int*   bat = (const int*)d_in[2];
    const float* W0  = (const float*)d_in[3];
    const float* b0  = (const float*)d_in[4];
    const float* W1  = (const float*)d_in[5];
    const float* a1s = (const float*)d_in[6];
    const float* a1d = (const float*)d_in[7];
    const float* b1  = (const float*)d_in[8];
    const float* W2  = (const float*)d_in[9];
    const float* a2s = (const float*)d_in[10];
    const float* a2d = (const float*)d_in[11];
    const float* b2  = (const float*)d_in[12];
    const float* W3  = (const float*)d_in[13];
    const float* a3s = (const float*)d_in[14];
    const float* a3d = (const float*)d_in[15];
    const float* b3  = (const float*)d_in[16];
    const float* Wf  = (const float*)d_in[17];
    const float* bf  = (const float*)d_in[18];
    float* out = (float*)d_out;

    // workspace layout (~184 MB)
    char* p = (char*)d_ws;
    unsigned short* bufA = (unsigned short*)p; p += (size_t)N_NODES * 2048 * 2;
    unsigned short* bufB = (unsigned short*)p; p += (size_t)N_NODES * 2048 * 2;
    unsigned short* h0   = (unsigned short*)p; p += (size_t)N_NODES * 128 * 2;
    unsigned short* W1t  = (unsigned short*)p; p += (size_t)2048 * 128 * 2;
    unsigned short* W2t  = (unsigned short*)p; p += (size_t)2048 * 2048 * 2;
    unsigned short* W3t  = (unsigned short*)p; p += (size_t)512 * 2048 * 2;
    float* es   = (float*)p; p += (size_t)N_NODES * 8 * 4;
    float* ed   = (float*)p; p += (size_t)N_NODES * 8 * 4;
    float* w_es = (float*)p; p += 128 * 8 * 4;
    float* w_ed = (float*)p; p += 128 * 8 * 4;
    int* counts  = (int*)p; p += (size_t)N_NODES * 4;
    int* row_ptr = (int*)p; p += (size_t)(N_NODES + 1) * 4;
    int* col     = (int*)p; p += (size_t)ET * 4;

    // --- CSR by dst (scan re-zeroes counts for fill) ---
    zero_kernel<<<(N_NODES + 255) / 256, 256, 0, stream>>>(counts, N_NODES);
    count_kernel<<<(ET + 255) / 256, 256, 0, stream>>>(ei, counts);
    scan_kernel<<<1, 256, 0, stream>>>(counts, row_ptr);
    fill_kernel<<<(ET + 255) / 256, 256, 0, stream>>>(ei, row_ptr, counts, col);

    // --- weight transposes + att fold, one launch ---
    prep_kernel<<<dim3(64, 64, 4), 256, 0, stream>>>(W1, W2, W3, a1s, a1d,
                                                     W1t, W2t, W3t, w_es, w_ed);

    // --- embed + layer-1 logits fused ---
    gemm0es_kernel<<<N_NODES, 128, 0, stream>>>(x, W0, b0, w_es, w_ed, h0, es, ed);

    dim3 g12(2048 / 128, (N_NODES + 127) / 128);   // (16, 157)
    dim3 g3(512 / 128, (N_NODES + 127) / 128);     // (4, 157)
    int aggb = (N_NODES + 3) / 4;                  // wave per dst, 4 per block

    // --- layer 1 (aggregate-then-transform) ---
    agg1_wave<<<aggb, 256, 0, stream>>>(h0, es, ed, row_ptr, col, bufB);   // bufB[:, :1024]
    gemm_mfma_h1<<<g12, 256, 0, stream>>>(bufB, W1t, b1, bufA, N_NODES);   // bufA = h1

    // --- layer 2 ---
    gemm_mfma<<<g12, 256, 0, stream>>>(bufA, W2t, bufB, N_NODES, 2048, 2048);
    att8_kernel<<<N_NODES, 256, 0, stream>>>(bufB, a2s, a2d, es, ed);
    agg_wave<8, 256><<<aggb, 256, 0, stream>>>(bufB, es, ed, row_ptr, col, b2, bufA);

    // --- layer 3 ---
    gemm_mfma<<<g3, 256, 0, stream>>>(bufA, W3t, bufB, N_NODES, 512, 2048);
    att1_kernel<<<N_NODES, 64, 0, stream>>>(bufB, a3s, a3d, es, ed);
    agg_wave<1, 512><<<aggb, 256, 0, stream>>>(bufB, es, ed, row_ptr, col, b3, bufA);

    // --- fused pool + final ---
    poolfinal_kernel<<<G_GRAPHS, 512, 0, stream>>>(bufA, bat, Wf, bf, out);
}

// Round 10
// 749.631 us; speedup vs baseline: 1.3802x; 1.3802x over previous
//
#include <hip/hip_runtime.h>
#include <hip/hip_bf16.h>

#define N_NODES 20000
#define N_EDGES 100000
#define ET (N_EDGES + N_NODES)   // 120000 incl. self-loops
#define G_GRAPHS 16
#define SLOPE 0.2f

using short8  = __attribute__((ext_vector_type(8))) short;
using floatx4 = __attribute__((ext_vector_type(4))) float;

__device__ __forceinline__ float lrelu(float x) { return x > 0.f ? x : SLOPE * x; }

__device__ __forceinline__ float b2f(unsigned short u) {
    union { unsigned int i; float f; } v; v.i = ((unsigned int)u) << 16; return v.f;
}
__device__ __forceinline__ unsigned short f2b(float f) {
    union { float f; unsigned int i; } v; v.f = f;
    unsigned int i = v.i;
    return (unsigned short)((i + 0x7fffu + ((i >> 16) & 1u)) >> 16);  // RNE
}

__device__ __forceinline__ void gld16(const void* g, void* l) {
    __builtin_amdgcn_global_load_lds((const __attribute__((address_space(1))) void*)g,
                                     (__attribute__((address_space(3))) void*)l, 16, 0, 0);
}

__device__ int dev_lower_bound(const int* a, int n, int key) {
    int lo = 0, hi = n;
    while (lo < hi) { int mid = (lo + hi) >> 1; if (a[mid] < key) lo = mid + 1; else hi = mid; }
    return lo;
}

__global__ void zero_kernel(int* __restrict__ p, int n) {
    int i = blockIdx.x * blockDim.x + threadIdx.x;
    if (i < n) p[i] = 0;
}

// ---------------- CSR build (by dst) ----------------
__global__ void count_kernel(const int* __restrict__ ei, int* __restrict__ counts) {
    int e = blockIdx.x * blockDim.x + threadIdx.x;
    if (e >= ET) return;
    int dst = (e < N_EDGES) ? ei[N_EDGES + e] : (e - N_EDGES);
    atomicAdd(&counts[dst], 1);
}

// scan also re-zeroes counts so fill can reuse it as a cursor (saves one launch)
__global__ void scan_kernel(int* __restrict__ counts, int* __restrict__ row_ptr) {
    __shared__ int sums[256];
    int t = threadIdx.x;
    const int CH = (N_NODES + 255) / 256;
    int base = t * CH;
    int s = 0;
    for (int i = 0; i < CH; i++) { int idx = base + i; if (idx < N_NODES) s += counts[idx]; }
    sums[t] = s;
    __syncthreads();
    for (int off = 1; off < 256; off <<= 1) {
        int v = (t >= off) ? sums[t - off] : 0;
        __syncthreads();
        sums[t] += v;
        __syncthreads();
    }
    int run = (t == 0) ? 0 : sums[t - 1];
    for (int i = 0; i < CH; i++) {
        int idx = base + i;
        if (idx < N_NODES) {
            int c = counts[idx];
            row_ptr[idx] = run;
            run += c;
            counts[idx] = 0;
        }
    }
    if (t == 255) row_ptr[N_NODES] = run;
}

__global__ void fill_kernel(const int* __restrict__ ei, const int* __restrict__ row_ptr,
                            int* __restrict__ fill_cnt, int* __restrict__ col) {
    int e = blockIdx.x * blockDim.x + threadIdx.x;
    if (e >= ET) return;
    int src, dst;
    if (e < N_EDGES) { src = ei[e]; dst = ei[N_EDGES + e]; }
    else             { src = dst = e - N_EDGES; }
    int pos = atomicAdd(&fill_cnt[dst], 1);
    col[row_ptr[dst] + pos] = src;
}

// ---------------- prep megakernel: 3 weight transposes (z=0..2) + wes fold (z=3) ----------
__global__ void prep_kernel(const float* __restrict__ W1, const float* __restrict__ W2,
                            const float* __restrict__ W3, const float* __restrict__ a1s,
                            const float* __restrict__ a1d, unsigned short* __restrict__ W1t,
                            unsigned short* __restrict__ W2t, unsigned short* __restrict__ W3t,
                            float* __restrict__ w_es, float* __restrict__ w_ed) {
    int z = blockIdx.z;
    if (z == 3) {   // fold a1s/a1d into W1: w_es[k][hd] = <W1[k, hd*256:...], a1s[hd]>
        if (blockIdx.x >= 8 || blockIdx.y > 0 || threadIdx.x >= 128) return;
        int hd = blockIdx.x, k = threadIdx.x;
        const float* w   = W1 + (size_t)k * 2048 + hd * 256;
        const float* as_ = a1s + hd * 256;
        const float* ad_ = a1d + hd * 256;
        float s1 = 0.f, s2 = 0.f;
        for (int c = 0; c < 256; c++) { float wv = w[c]; s1 += wv * as_[c]; s2 += wv * ad_[c]; }
        w_es[k * 8 + hd] = s1;
        w_ed[k * 8 + hd] = s2;
        return;
    }
    const float* W; unsigned short* Wt; int K, N;
    if (z == 0)      { W = W1; Wt = W1t; K = 128;  N = 2048; }
    else if (z == 1) { W = W2; Wt = W2t; K = 2048; N = 2048; }
    else             { W = W3; Wt = W3t; K = 2048; N = 512;  }
    int bn = blockIdx.x * 32, bk = blockIdx.y * 32;
    if (bn >= N || bk >= K) return;
    __shared__ float tile[32][33];
    int tx = threadIdx.x & 31, ty = threadIdx.x >> 5;
#pragma unroll
    for (int p = 0; p < 32; p += 8)
        tile[ty + p][tx] = W[(size_t)(bk + ty + p) * N + bn + tx];
    __syncthreads();
#pragma unroll
    for (int p = 0; p < 32; p += 8)
        Wt[(size_t)(bn + ty + p) * K + bk + tx] = f2b(tile[tx][ty + p]);
}

// ---------------- GEMM0 + layer-1 logits fused ----------------
__global__ void gemm0es_kernel(const float* __restrict__ x, const float* __restrict__ W0,
                               const float* __restrict__ b0, const float* __restrict__ w_es,
                               const float* __restrict__ w_ed, unsigned short* __restrict__ h0,
                               float* __restrict__ es, float* __restrict__ ed) {
    __shared__ float xr[32];
    __shared__ float red[2][16];
    int n = blockIdx.x, t = threadIdx.x;  // 128 threads = 2 waves
    if (t < 32) xr[t] = x[n * 32 + t];
    __syncthreads();
    float acc = 0.f;
#pragma unroll
    for (int k = 0; k < 32; k++) acc += xr[k] * W0[k * 128 + t];
    float h = lrelu(acc + b0[t]);
    h0[(size_t)n * 128 + t] = f2b(h);
    float p[16];
#pragma unroll
    for (int hd = 0; hd < 8; hd++) {
        p[hd]     = h * w_es[t * 8 + hd];
        p[8 + hd] = h * w_ed[t * 8 + hd];
    }
#pragma unroll
    for (int m = 1; m < 64; m <<= 1)
#pragma unroll
        for (int i = 0; i < 16; i++) p[i] += __shfl_xor(p[i], m);
    int w = t >> 6, l = t & 63;
    if (l == 0)
#pragma unroll
        for (int i = 0; i < 16; i++) red[w][i] = p[i];
    __syncthreads();
    if (t < 8)       es[n * 8 + t] = red[0][t] + red[1][t];
    else if (t < 16) ed[n * 8 + (t - 8)] = red[0][t] + red[1][t];
}

// ---------------- layer-1 aggregation over 128-dim input ----------------
__global__ __launch_bounds__(256) void agg1_wave(const unsigned short* __restrict__ h0,
                                                 const float* __restrict__ es,
                                                 const float* __restrict__ ed,
                                                 const int* __restrict__ row_ptr,
                                                 const int* __restrict__ col,
                                                 unsigned short* __restrict__ outp) {
    int wv = threadIdx.x >> 6, l = threadIdx.x & 63;
    int v = blockIdx.x * 4 + wv;
    if (v >= N_NODES) return;
    int rs = row_ptr[v], deg = row_ptr[v + 1] - rs;
    float edv[8], den[8], a0[8], a1[8];
#pragma unroll
    for (int hd = 0; hd < 8; hd++) { edv[hd] = ed[v * 8 + hd]; den[hd] = 0.f; a0[hd] = 0.f; a1[hd] = 0.f; }
    int sN = (deg > 0) ? col[rs] : 0;
    for (int e = 0; e < deg; e++) {
        int s = sN;
        if (e + 1 < deg) sN = col[rs + e + 1];
        unsigned int u = *(const unsigned int*)&h0[(size_t)s * 128 + l * 2];
        float x0 = b2f((unsigned short)(u & 0xffff)), x1 = b2f((unsigned short)(u >> 16));
#pragma unroll
        for (int hd = 0; hd < 8; hd++) {
            float a = __expf(lrelu(es[s * 8 + hd] + edv[hd]));
            den[hd] += a;
            a0[hd] += a * x0;
            a1[hd] += a * x1;
        }
    }
#pragma unroll
    for (int hd = 0; hd < 8; hd++) {
        float inv = 1.f / (den[hd] + 1e-16f);
        unsigned int o = (unsigned int)f2b(a0[hd] * inv) | ((unsigned int)f2b(a1[hd] * inv) << 16);
        *(unsigned int*)&outp[(size_t)v * 1024 + hd * 128 + l * 2] = o;
    }
}

// ---------------- MFMA GEMM, BK=64: C[M,N] bf16 = A[M,K] @ Bt[N,K] ----------------
__global__ __launch_bounds__(256) void gemm_mfma(const unsigned short* __restrict__ A,
                                                 const unsigned short* __restrict__ Bt,
                                                 unsigned short* __restrict__ C,
                                                 int M, int N, int K) {
    __shared__ __align__(16) unsigned short As[128][64];
    __shared__ __align__(16) unsigned short Bs[128][64];
    int t = threadIdx.x;
    int w = t >> 6, l = t & 63;
    int r0 = blockIdx.y * 128, c0 = blockIdx.x * 128;
    int wr = (w >> 1) * 64, wc = (w & 1) * 64;
    int srow = l >> 3;                          // 0..7: staging row within 8-row group
    int gcb  = (l & 7) ^ srow;                  // swizzled global colblock (row&7 == srow)
    int m16 = l & 15, qb = l >> 4;
    floatx4 acc[4][4] = {};

    for (int k0 = 0; k0 < K; k0 += 64) {
        __syncthreads();
#pragma unroll
        for (int q = 0; q < 4; q++) {
            int row = w * 32 + q * 8 + srow;
            int ga = min(r0 + row, M - 1);
            gld16(A + (size_t)ga * K + k0 + gcb * 8, &As[w * 32 + q * 8][0]);
            gld16(Bt + (size_t)(c0 + row) * K + k0 + gcb * 8, &Bs[w * 32 + q * 8][0]);
        }
        __syncthreads();
#pragma unroll
        for (int kh = 0; kh < 2; kh++) {
            int roff = (((kh * 4 + qb) ^ (m16 & 7)) * 8);
            short8 af[4], bfr[4];
#pragma unroll
            for (int i = 0; i < 4; i++) af[i] = *(const short8*)&As[wr + i * 16 + m16][roff];
#pragma unroll
            for (int j = 0; j < 4; j++) bfr[j] = *(const short8*)&Bs[wc + j * 16 + m16][roff];
#pragma unroll
            for (int i = 0; i < 4; i++)
#pragma unroll
                for (int j = 0; j < 4; j++)
                    acc[i][j] = __builtin_amdgcn_mfma_f32_16x16x32_bf16(bfr[j], af[i], acc[i][j], 0, 0, 0);
        }
    }
    int quad = l >> 4;
#pragma unroll
    for (int i = 0; i < 4; i++) {
        int r = r0 + wr + i * 16 + m16;
        if (r < M) {
#pragma unroll
            for (int j = 0; j < 4; j++) {
                int c = c0 + wc + j * 16 + quad * 4;
                ushort4 o = make_ushort4(f2b(acc[i][j][0]), f2b(acc[i][j][1]),
                                         f2b(acc[i][j][2]), f2b(acc[i][j][3]));
                *(ushort4*)&C[(size_t)r * N + c] = o;
            }
        }
    }
}

// ---------------- layer-1 per-head GEMM (BK=64): C[M,2048] = A_head[M,128]@W1t + b1, lrelu --
__global__ __launch_bounds__(256) void gemm_mfma_h1(const unsigned short* __restrict__ A,
                                                    const unsigned short* __restrict__ Bt,
                                                    const float* __restrict__ bias,
                                                    unsigned short* __restrict__ C,
                                                    int M) {
    const int N = 2048, K = 128;
    __shared__ __align__(16) unsigned short As[128][64];
    __shared__ __align__(16) unsigned short Bs[128][64];
    int t = threadIdx.x;
    int w = t >> 6, l = t & 63;
    int r0 = blockIdx.y * 128, c0 = blockIdx.x * 128;
    int wr = (w >> 1) * 64, wc = (w & 1) * 64;
    int srow = l >> 3;
    int gcb  = (l & 7) ^ srow;
    int m16 = l & 15, qb = l >> 4;
    int aoff = (c0 >> 8) * 128;                 // head * 128
    floatx4 acc[4][4] = {};

    for (int k0 = 0; k0 < K; k0 += 64) {
        __syncthreads();
#pragma unroll
        for (int q = 0; q < 4; q++) {
            int row = w * 32 + q * 8 + srow;
            int ga = min(r0 + row, M - 1);
            gld16(A + (size_t)ga * 1024 + aoff + k0 + gcb * 8, &As[w * 32 + q * 8][0]);
            gld16(Bt + (size_t)(c0 + row) * K + k0 + gcb * 8, &Bs[w * 32 + q * 8][0]);
        }
        __syncthreads();
#pragma unroll
        for (int kh = 0; kh < 2; kh++) {
            int roff = (((kh * 4 + qb) ^ (m16 & 7)) * 8);
            short8 af[4], bfr[4];
#pragma unroll
            for (int i = 0; i < 4; i++) af[i] = *(const short8*)&As[wr + i * 16 + m16][roff];
#pragma unroll
            for (int j = 0; j < 4; j++) bfr[j] = *(const short8*)&Bs[wc + j * 16 + m16][roff];
#pragma unroll
            for (int i = 0; i < 4; i++)
#pragma unroll
                for (int j = 0; j < 4; j++)
                    acc[i][j] = __builtin_amdgcn_mfma_f32_16x16x32_bf16(bfr[j], af[i], acc[i][j], 0, 0, 0);
        }
    }
    int quad = l >> 4;
#pragma unroll
    for (int i = 0; i < 4; i++) {
        int r = r0 + wr + i * 16 + m16;
        if (r < M) {
#pragma unroll
            for (int j = 0; j < 4; j++) {
                int c = c0 + wc + j * 16 + quad * 4;
                ushort4 o = make_ushort4(f2b(lrelu(acc[i][j][0] + bias[c + 0])),
                                         f2b(lrelu(acc[i][j][1] + bias[c + 1])),
                                         f2b(lrelu(acc[i][j][2] + bias[c + 2])),
                                         f2b(lrelu(acc[i][j][3] + bias[c + 3])));
                *(ushort4*)&C[(size_t)r * N + c] = o;
            }
        }
    }
}

// ---------------- attention logits (layers 2,3) ----------------
__global__ void att8_kernel(const unsigned short* __restrict__ h, const float* __restrict__ a_s,
                            const float* __restrict__ a_d, float* __restrict__ es,
                            float* __restrict__ ed) {
    int n = blockIdx.x, t = threadIdx.x;  // 256 = 8 heads x 32 lanes
    int hd = t >> 5, l = t & 31;
    const unsigned short* hr = h + (size_t)n * 2048 + hd * 256 + l * 8;
    const float* as_ = a_s + hd * 256 + l * 8;
    const float* ad_ = a_d + hd * 256 + l * 8;
    uint4 u = *(const uint4*)hr;
    float v[8] = { b2f((unsigned short)(u.x & 0xffff)), b2f((unsigned short)(u.x >> 16)),
                   b2f((unsigned short)(u.y & 0xffff)), b2f((unsigned short)(u.y >> 16)),
                   b2f((unsigned short)(u.z & 0xffff)), b2f((unsigned short)(u.z >> 16)),
                   b2f((unsigned short)(u.w & 0xffff)), b2f((unsigned short)(u.w >> 16)) };
    float s1 = 0.f, s2 = 0.f;
#pragma unroll
    for (int j = 0; j < 8; j++) { s1 += v[j] * as_[j]; s2 += v[j] * ad_[j]; }
    for (int m = 16; m >= 1; m >>= 1) { s1 += __shfl_xor(s1, m); s2 += __shfl_xor(s2, m); }
    if (l == 0) { es[n * 8 + hd] = s1; ed[n * 8 + hd] = s2; }
}

__global__ void att1_kernel(const unsigned short* __restrict__ h, const float* __restrict__ a_s,
                            const float* __restrict__ a_d, float* __restrict__ es,
                            float* __restrict__ ed) {
    int n = blockIdx.x, l = threadIdx.x;  // 64 threads
    const unsigned short* hr = h + (size_t)n * 512 + l * 8;
    const float* as_ = a_s + l * 8;
    const float* ad_ = a_d + l * 8;
    uint4 u = *(const uint4*)hr;
    float v[8] = { b2f((unsigned short)(u.x & 0xffff)), b2f((unsigned short)(u.x >> 16)),
                   b2f((unsigned short)(u.y & 0xffff)), b2f((unsigned short)(u.y >> 16)),
                   b2f((unsigned short)(u.z & 0xffff)), b2f((unsigned short)(u.z >> 16)),
                   b2f((unsigned short)(u.w & 0xffff)), b2f((unsigned short)(u.w >> 16)) };
    float s1 = 0.f, s2 = 0.f;
#pragma unroll
    for (int j = 0; j < 8; j++) { s1 += v[j] * as_[j]; s2 += v[j] * ad_[j]; }
    for (int m = 32; m >= 1; m >>= 1) { s1 += __shfl_xor(s1, m); s2 += __shfl_xor(s2, m); }
    if (l == 0) { es[n] = s1; ed[n] = s2; }
}

// ---------------- wave-per-dst GAT aggregation, edge-unrolled x2 ----------------
template <int H, int C>
__global__ __launch_bounds__(256) void agg_wave(const unsigned short* __restrict__ hmid,
                                                const float* __restrict__ es,
                                                const float* __restrict__ ed,
                                                const int* __restrict__ row_ptr,
                                                const int* __restrict__ col,
                                                const float* __restrict__ bias,
                                                unsigned short* __restrict__ out) {
    constexpr int HC = H * C;
    constexpr int CH = HC / 512;            // uint4 chunks per lane: 4 (2048) or 1 (512)
    int wv = threadIdx.x >> 6, l = threadIdx.x & 63;
    int v = blockIdx.x * 4 + wv;
    if (v >= N_NODES) return;
    int rs = row_ptr[v], deg = row_ptr[v + 1] - rs;
    int hd[CH];
    float edv[CH], den[CH], acc[CH][8];
#pragma unroll
    for (int c = 0; c < CH; c++) {
        hd[c] = (c * 512 + l * 8) / C;
        edv[c] = ed[v * H + hd[c]];
        den[c] = 0.f;
#pragma unroll
        for (int k = 0; k < 8; k++) acc[c][k] = 0.f;
    }
    int e = 0;
    for (; e + 2 <= deg; e += 2) {          // two independent gather chains in flight
        int s0 = col[rs + e], s1 = col[rs + e + 1];
        const unsigned short* hr0 = hmid + (size_t)s0 * HC + l * 8;
        const unsigned short* hr1 = hmid + (size_t)s1 * HC + l * 8;
        uint4 u0[CH], u1[CH];
#pragma unroll
        for (int c = 0; c < CH; c++) { u0[c] = *(const uint4*)(hr0 + c * 512); u1[c] = *(const uint4*)(hr1 + c * 512); }
        float ex0[CH], ex1[CH];
#pragma unroll
        for (int c = 0; c < CH; c++) {
            ex0[c] = __expf(lrelu(es[s0 * H + hd[c]] + edv[c]));
            ex1[c] = __expf(lrelu(es[s1 * H + hd[c]] + edv[c]));
            den[c] += ex0[c] + ex1[c];
        }
#pragma unroll
        for (int c = 0; c < CH; c++) {
            float a = ex0[c], b = ex1[c];
            acc[c][0] += a * b2f((unsigned short)(u0[c].x & 0xffff)) + b * b2f((unsigned short)(u1[c].x & 0xffff));
            acc[c][1] += a * b2f((unsigned short)(u0[c].x >> 16))    + b * b2f((unsigned short)(u1[c].x >> 16));
            acc[c][2] += a * b2f((unsigned short)(u0[c].y & 0xffff)) + b * b2f((unsigned short)(u1[c].y & 0xffff));
            acc[c][3] += a * b2f((unsigned short)(u0[c].y >> 16))    + b * b2f((unsigned short)(u1[c].y >> 16));
            acc[c][4] += a * b2f((unsigned short)(u0[c].z & 0xffff)) + b * b2f((unsigned short)(u1[c].z & 0xffff));
            acc[c][5] += a * b2f((unsigned short)(u0[c].z >> 16))    + b * b2f((unsigned short)(u1[c].z >> 16));
            acc[c][6] += a * b2f((unsigned short)(u0[c].w & 0xffff)) + b * b2f((unsigned short)(u1[c].w & 0xffff));
            acc[c][7] += a * b2f((unsigned short)(u0[c].w >> 16))    + b * b2f((unsigned short)(u1[c].w >> 16));
        }
    }
    if (e < deg) {
        int s = col[rs + e];
        const unsigned short* hr = hmid + (size_t)s * HC + l * 8;
#pragma unroll
        for (int c = 0; c < CH; c++) {
            uint4 u = *(const uint4*)(hr + c * 512);
            float a = __expf(lrelu(es[s * H + hd[c]] + edv[c]));
            den[c] += a;
            acc[c][0] += a * b2f((unsigned short)(u.x & 0xffff));
            acc[c][1] += a * b2f((unsigned short)(u.x >> 16));
            acc[c][2] += a * b2f((unsigned short)(u.y & 0xffff));
            acc[c][3] += a * b2f((unsigned short)(u.y >> 16));
            acc[c][4] += a * b2f((unsigned short)(u.z & 0xffff));
            acc[c][5] += a * b2f((unsigned short)(u.z >> 16));
            acc[c][6] += a * b2f((unsigned short)(u.w & 0xffff));
            acc[c][7] += a * b2f((unsigned short)(u.w >> 16));
        }
    }
#pragma unroll
    for (int c = 0; c < CH; c++) {
        float inv = 1.f / (den[c] + 1e-16f);
        unsigned short o[8];
#pragma unroll
        for (int k = 0; k < 8; k++)
            o[k] = f2b(lrelu(acc[c][k] * inv + bias[c * 512 + l * 8 + k]));
        *(uint4*)&out[(size_t)v * HC + c * 512 + l * 8] = *(const uint4*)o;
    }
}

// ---------------- mean pool (chunked partial sums + atomics; 157 blocks) ----------------
__global__ void pool_kernel(const unsigned short* __restrict__ h3, const int* __restrict__ batch,
                            float* __restrict__ msum) {
    int b0 = blockIdx.x * 128, t = threadIdx.x;  // 256 thr, 2 cols each
    int nend = min(b0 + 128, N_NODES);
    int curg = batch[b0];
    float s0 = 0.f, s1 = 0.f;
    for (int n = b0; n < nend; n++) {
        int g = batch[n];
        if (g != curg) {
            atomicAdd(&msum[curg * 512 + t * 2], s0);
            atomicAdd(&msum[curg * 512 + t * 2 + 1], s1);
            s0 = s1 = 0.f; curg = g;
        }
        unsigned int u = *(const unsigned int*)&h3[(size_t)n * 512 + t * 2];
        s0 += b2f((unsigned short)(u & 0xffff));
        s1 += b2f((unsigned short)(u >> 16));
    }
    atomicAdd(&msum[curg * 512 + t * 2], s0);
    atomicAdd(&msum[curg * 512 + t * 2 + 1], s1);
}

// ---------------- final: mean[16,512]@Wf[512,512]+bf, leaky ----------------
__global__ void final_kernel(const float* __restrict__ msum, const int* __restrict__ batch,
                             const float* __restrict__ Wf, const float* __restrict__ bf,
                             float* __restrict__ out) {
    int g = blockIdx.x, t = threadIdx.x;  // 256 threads
    __shared__ float mr[512];
    __shared__ float sinv;
    if (t == 0) {
        int st = dev_lower_bound(batch, N_NODES, g);
        int en = dev_lower_bound(batch, N_NODES, g + 1);
        sinv = 1.f / fmaxf((float)(en - st), 1.f);
    }
    __syncthreads();
    for (int c = t; c < 512; c += 256) mr[c] = msum[g * 512 + c] * sinv;
    __syncthreads();
    for (int j = t; j < 512; j += 256) {
        float s = 0.f;
        for (int k = 0; k < 512; k++) s += mr[k] * Wf[k * 512 + j];
        out[g * 512 + j] = lrelu(s + bf[j]);
    }
}

extern "C" void kernel_launch(void* const* d_in, const int* in_sizes, int n_in,
                              void* d_out, int out_size, void* d_ws, size_t ws_size,
                              hipStream_t stream) {
    const float* x   = (const float*)d_in[0];
    const int*   ei  = (const int*)d_in[1];
    const int*   bat = (const int*)d_in[2];
    const float* W0  = (const float*)d_in[3];
    const float* b0  = (const float*)d_in[4];
    const float* W1  = (const float*)d_in[5];
    const float* a1s = (const float*)d_in[6];
    const float* a1d = (const float*)d_in[7];
    const float* b1  = (const float*)d_in[8];
    const float* W2  = (const float*)d_in[9];
    const float* a2s = (const float*)d_in[10];
    const float* a2d = (const float*)d_in[11];
    const float* b2  = (const float*)d_in[12];
    const float* W3  = (const float*)d_in[13];
    const float* a3s = (const float*)d_in[14];
    const float* a3d = (const float*)d_in[15];
    const float* b3  = (const float*)d_in[16];
    const float* Wf  = (const float*)d_in[17];
    const float* bf  = (const float*)d_in[18];
    float* out = (float*)d_out;

    // workspace layout (~184 MB)
    char* p = (char*)d_ws;
    unsigned short* bufA = (unsigned short*)p; p += (size_t)N_NODES * 2048 * 2;
    unsigned short* bufB = (unsigned short*)p; p += (size_t)N_NODES * 2048 * 2;
    unsigned short* h0   = (unsigned short*)p; p += (size_t)N_NODES * 128 * 2;
    unsigned short* W1t  = (unsigned short*)p; p += (size_t)2048 * 128 * 2;
    unsigned short* W2t  = (unsigned short*)p; p += (size_t)2048 * 2048 * 2;
    unsigned short* W3t  = (unsigned short*)p; p += (size_t)512 * 2048 * 2;
    float* es   = (float*)p; p += (size_t)N_NODES * 8 * 4;
    float* ed   = (float*)p; p += (size_t)N_NODES * 8 * 4;
    float* w_es = (float*)p; p += 128 * 8 * 4;
    float* w_ed = (float*)p; p += 128 * 8 * 4;
    // counts + msum contiguous -> one zero launch covers both
    int* counts  = (int*)p; p += (size_t)N_NODES * 4;
    float* msum  = (float*)p; p += 16 * 512 * 4;
    int* row_ptr = (int*)p; p += (size_t)(N_NODES + 1) * 4;
    int* col     = (int*)p; p += (size_t)ET * 4;
    const int ZN = N_NODES + 16 * 512;   // counts + msum, in 4B words

    // --- CSR by dst (scan re-zeroes counts for fill) + msum zero ---
    zero_kernel<<<(ZN + 255) / 256, 256, 0, stream>>>(counts, ZN);
    count_kernel<<<(ET + 255) / 256, 256, 0, stream>>>(ei, counts);
    scan_kernel<<<1, 256, 0, stream>>>(counts, row_ptr);
    fill_kernel<<<(ET + 255) / 256, 256, 0, stream>>>(ei, row_ptr, counts, col);

    // --- weight transposes + att fold, one launch ---
    prep_kernel<<<dim3(64, 64, 4), 256, 0, stream>>>(W1, W2, W3, a1s, a1d,
                                                     W1t, W2t, W3t, w_es, w_ed);

    // --- embed + layer-1 logits fused ---
    gemm0es_kernel<<<N_NODES, 128, 0, stream>>>(x, W0, b0, w_es, w_ed, h0, es, ed);

    dim3 g12(2048 / 128, (N_NODES + 127) / 128);   // (16, 157)
    dim3 g3(512 / 128, (N_NODES + 127) / 128);     // (4, 157)
    int aggb = (N_NODES + 3) / 4;                  // wave per dst, 4 per block

    // --- layer 1 (aggregate-then-transform) ---
    agg1_wave<<<aggb, 256, 0, stream>>>(h0, es, ed, row_ptr, col, bufB);   // bufB[:, :1024]
    gemm_mfma_h1<<<g12, 256, 0, stream>>>(bufB, W1t, b1, bufA, N_NODES);   // bufA = h1

    // --- layer 2 ---
    gemm_mfma<<<g12, 256, 0, stream>>>(bufA, W2t, bufB, N_NODES, 2048, 2048);
    att8_kernel<<<N_NODES, 256, 0, stream>>>(bufB, a2s, a2d, es, ed);
    agg_wave<8, 256><<<aggb, 256, 0, stream>>>(bufB, es, ed, row_ptr, col, b2, bufA);

    // --- layer 3 ---
    gemm_mfma<<<g3, 256, 0, stream>>>(bufA, W3t, bufB, N_NODES, 512, 2048);
    att1_kernel<<<N_NODES, 64, 0, stream>>>(bufB, a3s, a3d, es, ed);
    agg_wave<1, 512><<<aggb, 256, 0, stream>>>(bufB, es, ed, row_ptr, col, b3, bufA);

    // --- pool + final (parallel pool: 157 blocks; final: 16 blocks) ---
    pool_kernel<<<(N_NODES + 127) / 128, 256, 0, stream>>>(bufA, bat, msum);
    final_kernel<<<G_GRAPHS, 256, 0, stream>>>(msum, bat, Wf, bf, out);
}

// Round 11
// 725.288 us; speedup vs baseline: 1.4265x; 1.0336x over previous
//
#include <hip/hip_runtime.h>
#include <hip/hip_bf16.h>

#define N_NODES 20000
#define N_EDGES 100000
#define ET (N_EDGES + N_NODES)   // 120000 incl. self-loops
#define G_GRAPHS 16
#define SLOPE 0.2f

using short8  = __attribute__((ext_vector_type(8))) short;
using floatx4 = __attribute__((ext_vector_type(4))) float;

__device__ __forceinline__ float lrelu(float x) { return x > 0.f ? x : SLOPE * x; }

__device__ __forceinline__ float b2f(unsigned short u) {
    union { unsigned int i; float f; } v; v.i = ((unsigned int)u) << 16; return v.f;
}
__device__ __forceinline__ unsigned short f2b(float f) {
    union { float f; unsigned int i; } v; v.f = f;
    unsigned int i = v.i;
    return (unsigned short)((i + 0x7fffu + ((i >> 16) & 1u)) >> 16);  // RNE
}

__device__ __forceinline__ void gld16(const void* g, void* l) {
    __builtin_amdgcn_global_load_lds((const __attribute__((address_space(1))) void*)g,
                                     (__attribute__((address_space(3))) void*)l, 16, 0, 0);
}

__device__ int dev_lower_bound(const int* a, int n, int key) {
    int lo = 0, hi = n;
    while (lo < hi) { int mid = (lo + hi) >> 1; if (a[mid] < key) lo = mid + 1; else hi = mid; }
    return lo;
}

__global__ void zero_kernel(int* __restrict__ p, int n) {
    int i = blockIdx.x * blockDim.x + threadIdx.x;
    if (i < n) p[i] = 0;
}

// ---------------- CSR build (by dst) ----------------
__global__ void count_kernel(const int* __restrict__ ei, int* __restrict__ counts) {
    int e = blockIdx.x * blockDim.x + threadIdx.x;
    if (e >= ET) return;
    int dst = (e < N_EDGES) ? ei[N_EDGES + e] : (e - N_EDGES);
    atomicAdd(&counts[dst], 1);
}

// single-block scan, 1024 threads (20 serial elems/thread); re-zeroes counts for fill
__global__ __launch_bounds__(1024) void scan_kernel(int* __restrict__ counts,
                                                    int* __restrict__ row_ptr) {
    __shared__ int sums[1024];
    int t = threadIdx.x;
    const int CH = (N_NODES + 1023) / 1024;   // 20
    int base = t * CH;
    int s = 0;
    for (int i = 0; i < CH; i++) { int idx = base + i; if (idx < N_NODES) s += counts[idx]; }
    sums[t] = s;
    __syncthreads();
    for (int off = 1; off < 1024; off <<= 1) {
        int v = (t >= off) ? sums[t - off] : 0;
        __syncthreads();
        sums[t] += v;
        __syncthreads();
    }
    int run = (t == 0) ? 0 : sums[t - 1];
    for (int i = 0; i < CH; i++) {
        int idx = base + i;
        if (idx < N_NODES) {
            int c = counts[idx];
            row_ptr[idx] = run;
            run += c;
            counts[idx] = 0;
        }
    }
    if (t == 1023) row_ptr[N_NODES] = run;
}

__global__ void fill_kernel(const int* __restrict__ ei, const int* __restrict__ row_ptr,
                            int* __restrict__ fill_cnt, int* __restrict__ col) {
    int e = blockIdx.x * blockDim.x + threadIdx.x;
    if (e >= ET) return;
    int src, dst;
    if (e < N_EDGES) { src = ei[e]; dst = ei[N_EDGES + e]; }
    else             { src = dst = e - N_EDGES; }
    int pos = atomicAdd(&fill_cnt[dst], 1);
    col[row_ptr[dst] + pos] = src;
}

// ---------------- prep megakernel: 3 weight transposes (z=0..2) + wes fold (z=3) ----------
__global__ void prep_kernel(const float* __restrict__ W1, const float* __restrict__ W2,
                            const float* __restrict__ W3, const float* __restrict__ a1s,
                            const float* __restrict__ a1d, unsigned short* __restrict__ W1t,
                            unsigned short* __restrict__ W2t, unsigned short* __restrict__ W3t,
                            float* __restrict__ w_es, float* __restrict__ w_ed) {
    int z = blockIdx.z;
    if (z == 3) {   // fold a1s/a1d into W1: w_es[k][hd] = <W1[k, hd*256:...], a1s[hd]>
        if (blockIdx.x >= 8 || blockIdx.y > 0 || threadIdx.x >= 128) return;
        int hd = blockIdx.x, k = threadIdx.x;
        const float* w   = W1 + (size_t)k * 2048 + hd * 256;
        const float* as_ = a1s + hd * 256;
        const float* ad_ = a1d + hd * 256;
        float s1 = 0.f, s2 = 0.f;
        for (int c = 0; c < 256; c++) { float wv = w[c]; s1 += wv * as_[c]; s2 += wv * ad_[c]; }
        w_es[k * 8 + hd] = s1;
        w_ed[k * 8 + hd] = s2;
        return;
    }
    const float* W; unsigned short* Wt; int K, N;
    if (z == 0)      { W = W1; Wt = W1t; K = 128;  N = 2048; }
    else if (z == 1) { W = W2; Wt = W2t; K = 2048; N = 2048; }
    else             { W = W3; Wt = W3t; K = 2048; N = 512;  }
    int bn = blockIdx.x * 32, bk = blockIdx.y * 32;
    if (bn >= N || bk >= K) return;
    __shared__ float tile[32][33];
    int tx = threadIdx.x & 31, ty = threadIdx.x >> 5;
#pragma unroll
    for (int p = 0; p < 32; p += 8)
        tile[ty + p][tx] = W[(size_t)(bk + ty + p) * N + bn + tx];
    __syncthreads();
#pragma unroll
    for (int p = 0; p < 32; p += 8)
        Wt[(size_t)(bn + ty + p) * K + bk + tx] = f2b(tile[tx][ty + p]);
}

// ---------------- GEMM0 + layer-1 logits fused ----------------
__global__ void gemm0es_kernel(const float* __restrict__ x, const float* __restrict__ W0,
                               const float* __restrict__ b0, const float* __restrict__ w_es,
                               const float* __restrict__ w_ed, unsigned short* __restrict__ h0,
                               float* __restrict__ es, float* __restrict__ ed) {
    __shared__ float xr[32];
    __shared__ float red[2][16];
    int n = blockIdx.x, t = threadIdx.x;  // 128 threads = 2 waves
    if (t < 32) xr[t] = x[n * 32 + t];
    __syncthreads();
    float acc = 0.f;
#pragma unroll
    for (int k = 0; k < 32; k++) acc += xr[k] * W0[k * 128 + t];
    float h = lrelu(acc + b0[t]);
    h0[(size_t)n * 128 + t] = f2b(h);
    float p[16];
#pragma unroll
    for (int hd = 0; hd < 8; hd++) {
        p[hd]     = h * w_es[t * 8 + hd];
        p[8 + hd] = h * w_ed[t * 8 + hd];
    }
#pragma unroll
    for (int m = 1; m < 64; m <<= 1)
#pragma unroll
        for (int i = 0; i < 16; i++) p[i] += __shfl_xor(p[i], m);
    int w = t >> 6, l = t & 63;
    if (l == 0)
#pragma unroll
        for (int i = 0; i < 16; i++) red[w][i] = p[i];
    __syncthreads();
    if (t < 8)       es[n * 8 + t] = red[0][t] + red[1][t];
    else if (t < 16) ed[n * 8 + (t - 8)] = red[0][t] + red[1][t];
}

// ---------------- layer-1 aggregation over 128-dim input ----------------
__global__ __launch_bounds__(256) void agg1_wave(const unsigned short* __restrict__ h0,
                                                 const float* __restrict__ es,
                                                 const float* __restrict__ ed,
                                                 const int* __restrict__ row_ptr,
                                                 const int* __restrict__ col,
                                                 unsigned short* __restrict__ outp) {
    int wv = threadIdx.x >> 6, l = threadIdx.x & 63;
    int v = blockIdx.x * 4 + wv;
    if (v >= N_NODES) return;
    int rs = row_ptr[v], deg = row_ptr[v + 1] - rs;
    float edv[8], den[8], a0[8], a1[8];
#pragma unroll
    for (int hd = 0; hd < 8; hd++) { edv[hd] = ed[v * 8 + hd]; den[hd] = 0.f; a0[hd] = 0.f; a1[hd] = 0.f; }
    int sN = (deg > 0) ? col[rs] : 0;
    for (int e = 0; e < deg; e++) {
        int s = sN;
        if (e + 1 < deg) sN = col[rs + e + 1];
        unsigned int u = *(const unsigned int*)&h0[(size_t)s * 128 + l * 2];
        float x0 = b2f((unsigned short)(u & 0xffff)), x1 = b2f((unsigned short)(u >> 16));
#pragma unroll
        for (int hd = 0; hd < 8; hd++) {
            float a = __expf(lrelu(es[s * 8 + hd] + edv[hd]));
            den[hd] += a;
            a0[hd] += a * x0;
            a1[hd] += a * x1;
        }
    }
#pragma unroll
    for (int hd = 0; hd < 8; hd++) {
        float inv = 1.f / (den[hd] + 1e-16f);
        unsigned int o = (unsigned int)f2b(a0[hd] * inv) | ((unsigned int)f2b(a1[hd] * inv) << 16);
        *(unsigned int*)&outp[(size_t)v * 1024 + hd * 128 + l * 2] = o;
    }
}

// ---------------- MFMA GEMM, BK=64: C[M,N] bf16 = A[M,K] @ Bt[N,K] ----------------
// yoff = row-tile offset (for M-split launches).
__global__ __launch_bounds__(256) void gemm_mfma(const unsigned short* __restrict__ A,
                                                 const unsigned short* __restrict__ Bt,
                                                 unsigned short* __restrict__ C,
                                                 int M, int N, int K, int yoff) {
    __shared__ __align__(16) unsigned short As[128][64];
    __shared__ __align__(16) unsigned short Bs[128][64];
    int t = threadIdx.x;
    int w = t >> 6, l = t & 63;
    int r0 = (blockIdx.y + yoff) * 128, c0 = blockIdx.x * 128;
    int wr = (w >> 1) * 64, wc = (w & 1) * 64;
    int srow = l >> 3;                          // 0..7: staging row within 8-row group
    int gcb  = (l & 7) ^ srow;                  // swizzled global colblock (row&7 == srow)
    int m16 = l & 15, qb = l >> 4;
    floatx4 acc[4][4] = {};

    for (int k0 = 0; k0 < K; k0 += 64) {
        __syncthreads();
#pragma unroll
        for (int q = 0; q < 4; q++) {
            int row = w * 32 + q * 8 + srow;
            int ga = min(r0 + row, M - 1);
            gld16(A + (size_t)ga * K + k0 + gcb * 8, &As[w * 32 + q * 8][0]);
            gld16(Bt + (size_t)(c0 + row) * K + k0 + gcb * 8, &Bs[w * 32 + q * 8][0]);
        }
        __syncthreads();
#pragma unroll
        for (int kh = 0; kh < 2; kh++) {
            int roff = (((kh * 4 + qb) ^ (m16 & 7)) * 8);
            short8 af[4], bfr[4];
#pragma unroll
            for (int i = 0; i < 4; i++) af[i] = *(const short8*)&As[wr + i * 16 + m16][roff];
#pragma unroll
            for (int j = 0; j < 4; j++) bfr[j] = *(const short8*)&Bs[wc + j * 16 + m16][roff];
#pragma unroll
            for (int i = 0; i < 4; i++)
#pragma unroll
                for (int j = 0; j < 4; j++)
                    acc[i][j] = __builtin_amdgcn_mfma_f32_16x16x32_bf16(bfr[j], af[i], acc[i][j], 0, 0, 0);
        }
    }
    int quad = l >> 4;
#pragma unroll
    for (int i = 0; i < 4; i++) {
        int r = r0 + wr + i * 16 + m16;
        if (r < M) {
#pragma unroll
            for (int j = 0; j < 4; j++) {
                int c = c0 + wc + j * 16 + quad * 4;
                ushort4 o = make_ushort4(f2b(acc[i][j][0]), f2b(acc[i][j][1]),
                                         f2b(acc[i][j][2]), f2b(acc[i][j][3]));
                *(ushort4*)&C[(size_t)r * N + c] = o;
            }
        }
    }
}

// ---------------- layer-1 per-head GEMM (BK=64): C[M,2048] = A_head[M,128]@W1t + b1, lrelu --
__global__ __launch_bounds__(256) void gemm_mfma_h1(const unsigned short* __restrict__ A,
                                                    const unsigned short* __restrict__ Bt,
                                                    const float* __restrict__ bias,
                                                    unsigned short* __restrict__ C,
                                                    int M) {
    const int N = 2048, K = 128;
    __shared__ __align__(16) unsigned short As[128][64];
    __shared__ __align__(16) unsigned short Bs[128][64];
    int t = threadIdx.x;
    int w = t >> 6, l = t & 63;
    int r0 = blockIdx.y * 128, c0 = blockIdx.x * 128;
    int wr = (w >> 1) * 64, wc = (w & 1) * 64;
    int srow = l >> 3;
    int gcb  = (l & 7) ^ srow;
    int m16 = l & 15, qb = l >> 4;
    int aoff = (c0 >> 8) * 128;                 // head * 128
    floatx4 acc[4][4] = {};

    for (int k0 = 0; k0 < K; k0 += 64) {
        __syncthreads();
#pragma unroll
        for (int q = 0; q < 4; q++) {
            int row = w * 32 + q * 8 + srow;
            int ga = min(r0 + row, M - 1);
            gld16(A + (size_t)ga * 1024 + aoff + k0 + gcb * 8, &As[w * 32 + q * 8][0]);
            gld16(Bt + (size_t)(c0 + row) * K + k0 + gcb * 8, &Bs[w * 32 + q * 8][0]);
        }
        __syncthreads();
#pragma unroll
        for (int kh = 0; kh < 2; kh++) {
            int roff = (((kh * 4 + qb) ^ (m16 & 7)) * 8);
            short8 af[4], bfr[4];
#pragma unroll
            for (int i = 0; i < 4; i++) af[i] = *(const short8*)&As[wr + i * 16 + m16][roff];
#pragma unroll
            for (int j = 0; j < 4; j++) bfr[j] = *(const short8*)&Bs[wc + j * 16 + m16][roff];
#pragma unroll
            for (int i = 0; i < 4; i++)
#pragma unroll
                for (int j = 0; j < 4; j++)
                    acc[i][j] = __builtin_amdgcn_mfma_f32_16x16x32_bf16(bfr[j], af[i], acc[i][j], 0, 0, 0);
        }
    }
    int quad = l >> 4;
#pragma unroll
    for (int i = 0; i < 4; i++) {
        int r = r0 + wr + i * 16 + m16;
        if (r < M) {
#pragma unroll
            for (int j = 0; j < 4; j++) {
                int c = c0 + wc + j * 16 + quad * 4;
                ushort4 o = make_ushort4(f2b(lrelu(acc[i][j][0] + bias[c + 0])),
                                         f2b(lrelu(acc[i][j][1] + bias[c + 1])),
                                         f2b(lrelu(acc[i][j][2] + bias[c + 2])),
                                         f2b(lrelu(acc[i][j][3] + bias[c + 3])));
                *(ushort4*)&C[(size_t)r * N + c] = o;
            }
        }
    }
}

// ---------------- attention logits (layers 2,3) ----------------
__global__ void att8_kernel(const unsigned short* __restrict__ h, const float* __restrict__ a_s,
                            const float* __restrict__ a_d, float* __restrict__ es,
                            float* __restrict__ ed) {
    int n = blockIdx.x, t = threadIdx.x;  // 256 = 8 heads x 32 lanes
    int hd = t >> 5, l = t & 31;
    const unsigned short* hr = h + (size_t)n * 2048 + hd * 256 + l * 8;
    const float* as_ = a_s + hd * 256 + l * 8;
    const float* ad_ = a_d + hd * 256 + l * 8;
    uint4 u = *(const uint4*)hr;
    float v[8] = { b2f((unsigned short)(u.x & 0xffff)), b2f((unsigned short)(u.x >> 16)),
                   b2f((unsigned short)(u.y & 0xffff)), b2f((unsigned short)(u.y >> 16)),
                   b2f((unsigned short)(u.z & 0xffff)), b2f((unsigned short)(u.z >> 16)),
                   b2f((unsigned short)(u.w & 0xffff)), b2f((unsigned short)(u.w >> 16)) };
    float s1 = 0.f, s2 = 0.f;
#pragma unroll
    for (int j = 0; j < 8; j++) { s1 += v[j] * as_[j]; s2 += v[j] * ad_[j]; }
    for (int m = 16; m >= 1; m >>= 1) { s1 += __shfl_xor(s1, m); s2 += __shfl_xor(s2, m); }
    if (l == 0) { es[n * 8 + hd] = s1; ed[n * 8 + hd] = s2; }
}

__global__ void att1_kernel(const unsigned short* __restrict__ h, const float* __restrict__ a_s,
                            const float* __restrict__ a_d, float* __restrict__ es,
                            float* __restrict__ ed) {
    int n = blockIdx.x, l = threadIdx.x;  // 64 threads
    const unsigned short* hr = h + (size_t)n * 512 + l * 8;
    const float* as_ = a_s + l * 8;
    const float* ad_ = a_d + l * 8;
    uint4 u = *(const uint4*)hr;
    float v[8] = { b2f((unsigned short)(u.x & 0xffff)), b2f((unsigned short)(u.x >> 16)),
                   b2f((unsigned short)(u.y & 0xffff)), b2f((unsigned short)(u.y >> 16)),
                   b2f((unsigned short)(u.z & 0xffff)), b2f((unsigned short)(u.z >> 16)),
                   b2f((unsigned short)(u.w & 0xffff)), b2f((unsigned short)(u.w >> 16)) };
    float s1 = 0.f, s2 = 0.f;
#pragma unroll
    for (int j = 0; j < 8; j++) { s1 += v[j] * as_[j]; s2 += v[j] * ad_[j]; }
    for (int m = 32; m >= 1; m >>= 1) { s1 += __shfl_xor(s1, m); s2 += __shfl_xor(s2, m); }
    if (l == 0) { es[n] = s1; ed[n] = s2; }
}

// ---------------- wave-per-dst GAT aggregation, edge-unrolled x2 ----------------
template <int H, int C>
__global__ __launch_bounds__(256) void agg_wave(const unsigned short* __restrict__ hmid,
                                                const float* __restrict__ es,
                                                const float* __restrict__ ed,
                                                const int* __restrict__ row_ptr,
                                                const int* __restrict__ col,
                                                const float* __restrict__ bias,
                                                unsigned short* __restrict__ out) {
    constexpr int HC = H * C;
    constexpr int CH = HC / 512;            // uint4 chunks per lane: 4 (2048) or 1 (512)
    int wv = threadIdx.x >> 6, l = threadIdx.x & 63;
    int v = blockIdx.x * 4 + wv;
    if (v >= N_NODES) return;
    int rs = row_ptr[v], deg = row_ptr[v + 1] - rs;
    int hd[CH];
    float edv[CH], den[CH], acc[CH][8];
#pragma unroll
    for (int c = 0; c < CH; c++) {
        hd[c] = (c * 512 + l * 8) / C;
        edv[c] = ed[v * H + hd[c]];
        den[c] = 0.f;
#pragma unroll
        for (int k = 0; k < 8; k++) acc[c][k] = 0.f;
    }
    int e = 0;
    for (; e + 2 <= deg; e += 2) {          // two independent gather chains in flight
        int s0 = col[rs + e], s1 = col[rs + e + 1];
        const unsigned short* hr0 = hmid + (size_t)s0 * HC + l * 8;
        const unsigned short* hr1 = hmid + (size_t)s1 * HC + l * 8;
        uint4 u0[CH], u1[CH];
#pragma unroll
        for (int c = 0; c < CH; c++) { u0[c] = *(const uint4*)(hr0 + c * 512); u1[c] = *(const uint4*)(hr1 + c * 512); }
        float ex0[CH], ex1[CH];
#pragma unroll
        for (int c = 0; c < CH; c++) {
            ex0[c] = __expf(lrelu(es[s0 * H + hd[c]] + edv[c]));
            ex1[c] = __expf(lrelu(es[s1 * H + hd[c]] + edv[c]));
            den[c] += ex0[c] + ex1[c];
        }
#pragma unroll
        for (int c = 0; c < CH; c++) {
            float a = ex0[c], b = ex1[c];
            acc[c][0] += a * b2f((unsigned short)(u0[c].x & 0xffff)) + b * b2f((unsigned short)(u1[c].x & 0xffff));
            acc[c][1] += a * b2f((unsigned short)(u0[c].x >> 16))    + b * b2f((unsigned short)(u1[c].x >> 16));
            acc[c][2] += a * b2f((unsigned short)(u0[c].y & 0xffff)) + b * b2f((unsigned short)(u1[c].y & 0xffff));
            acc[c][3] += a * b2f((unsigned short)(u0[c].y >> 16))    + b * b2f((unsigned short)(u1[c].y >> 16));
            acc[c][4] += a * b2f((unsigned short)(u0[c].z & 0xffff)) + b * b2f((unsigned short)(u1[c].z & 0xffff));
            acc[c][5] += a * b2f((unsigned short)(u0[c].z >> 16))    + b * b2f((unsigned short)(u1[c].z >> 16));
            acc[c][6] += a * b2f((unsigned short)(u0[c].w & 0xffff)) + b * b2f((unsigned short)(u1[c].w & 0xffff));
            acc[c][7] += a * b2f((unsigned short)(u0[c].w >> 16))    + b * b2f((unsigned short)(u1[c].w >> 16));
        }
    }
    if (e < deg) {
        int s = col[rs + e];
        const unsigned short* hr = hmid + (size_t)s * HC + l * 8;
#pragma unroll
        for (int c = 0; c < CH; c++) {
            uint4 u = *(const uint4*)(hr + c * 512);
            float a = __expf(lrelu(es[s * H + hd[c]] + edv[c]));
            den[c] += a;
            acc[c][0] += a * b2f((unsigned short)(u.x & 0xffff));
            acc[c][1] += a * b2f((unsigned short)(u.x >> 16));
            acc[c][2] += a * b2f((unsigned short)(u.y & 0xffff));
            acc[c][3] += a * b2f((unsigned short)(u.y >> 16));
            acc[c][4] += a * b2f((unsigned short)(u.z & 0xffff));
            acc[c][5] += a * b2f((unsigned short)(u.z >> 16));
            acc[c][6] += a * b2f((unsigned short)(u.w & 0xffff));
            acc[c][7] += a * b2f((unsigned short)(u.w >> 16));
        }
    }
#pragma unroll
    for (int c = 0; c < CH; c++) {
        float inv = 1.f / (den[c] + 1e-16f);
        unsigned short o[8];
#pragma unroll
        for (int k = 0; k < 8; k++)
            o[k] = f2b(lrelu(acc[c][k] * inv + bias[c * 512 + l * 8 + k]));
        *(uint4*)&out[(size_t)v * HC + c * 512 + l * 8] = *(const uint4*)o;
    }
}

// ---------------- mean pool (chunked partial sums + atomics; 157 blocks) ----------------
__global__ void pool_kernel(const unsigned short* __restrict__ h3, const int* __restrict__ batch,
                            float* __restrict__ msum) {
    int b0 = blockIdx.x * 128, t = threadIdx.x;  // 256 thr, 2 cols each
    int nend = min(b0 + 128, N_NODES);
    int curg = batch[b0];
    float s0 = 0.f, s1 = 0.f;
    for (int n = b0; n < nend; n++) {
        int g = batch[n];
        if (g != curg) {
            atomicAdd(&msum[curg * 512 + t * 2], s0);
            atomicAdd(&msum[curg * 512 + t * 2 + 1], s1);
            s0 = s1 = 0.f; curg = g;
        }
        unsigned int u = *(const unsigned int*)&h3[(size_t)n * 512 + t * 2];
        s0 += b2f((unsigned short)(u & 0xffff));
        s1 += b2f((unsigned short)(u >> 16));
    }
    atomicAdd(&msum[curg * 512 + t * 2], s0);
    atomicAdd(&msum[curg * 512 + t * 2 + 1], s1);
}

// ---------------- final: mean[16,512]@Wf[512,512]+bf, leaky ----------------
__global__ void final_kernel(const float* __restrict__ msum, const int* __restrict__ batch,
                             const float* __restrict__ Wf, const float* __restrict__ bf,
                             float* __restrict__ out) {
    int g = blockIdx.x, t = threadIdx.x;  // 256 threads
    __shared__ float mr[512];
    __shared__ float sinv;
    if (t == 0) {
        int st = dev_lower_bound(batch, N_NODES, g);
        int en = dev_lower_bound(batch, N_NODES, g + 1);
        sinv = 1.f / fmaxf((float)(en - st), 1.f);
    }
    __syncthreads();
    for (int c = t; c < 512; c += 256) mr[c] = msum[g * 512 + c] * sinv;
    __syncthreads();
    for (int j = t; j < 512; j += 256) {
        float s = 0.f;
        for (int k = 0; k < 512; k++) s += mr[k] * Wf[k * 512 + j];
        out[g * 512 + j] = lrelu(s + bf[j]);
    }
}

extern "C" void kernel_launch(void* const* d_in, const int* in_sizes, int n_in,
                              void* d_out, int out_size, void* d_ws, size_t ws_size,
                              hipStream_t stream) {
    const float* x   = (const float*)d_in[0];
    const int*   ei  = (const int*)d_in[1];
    const int*   bat = (const int*)d_in[2];
    const float* W0  = (const float*)d_in[3];
    const float* b0  = (const float*)d_in[4];
    const float* W1  = (const float*)d_in[5];
    const float* a1s = (const float*)d_in[6];
    const float* a1d = (const float*)d_in[7];
    const float* b1  = (const float*)d_in[8];
    const float* W2  = (const float*)d_in[9];
    const float* a2s = (const float*)d_in[10];
    const float* a2d = (const float*)d_in[11];
    const float* b2  = (const float*)d_in[12];
    const float* W3  = (const float*)d_in[13];
    const float* a3s = (const float*)d_in[14];
    const float* a3d = (const float*)d_in[15];
    const float* b3  = (const float*)d_in[16];
    const float* Wf  = (const float*)d_in[17];
    const float* bf  = (const float*)d_in[18];
    float* out = (float*)d_out;

    // workspace layout (~184 MB)
    char* p = (char*)d_ws;
    unsigned short* bufA = (unsigned short*)p; p += (size_t)N_NODES * 2048 * 2;
    unsigned short* bufB = (unsigned short*)p; p += (size_t)N_NODES * 2048 * 2;
    unsigned short* h0   = (unsigned short*)p; p += (size_t)N_NODES * 128 * 2;
    unsigned short* W1t  = (unsigned short*)p; p += (size_t)2048 * 128 * 2;
    unsigned short* W2t  = (unsigned short*)p; p += (size_t)2048 * 2048 * 2;
    unsigned short* W3t  = (unsigned short*)p; p += (size_t)512 * 2048 * 2;
    float* es   = (float*)p; p += (size_t)N_NODES * 8 * 4;
    float* ed   = (float*)p; p += (size_t)N_NODES * 8 * 4;
    float* w_es = (float*)p; p += 128 * 8 * 4;
    float* w_ed = (float*)p; p += 128 * 8 * 4;
    // counts + msum contiguous -> one zero launch covers both
    int* counts  = (int*)p; p += (size_t)N_NODES * 4;
    float* msum  = (float*)p; p += 16 * 512 * 4;
    int* row_ptr = (int*)p; p += (size_t)(N_NODES + 1) * 4;
    int* col     = (int*)p; p += (size_t)ET * 4;
    const int ZN = N_NODES + 16 * 512;   // counts + msum, in 4B words

    // --- CSR by dst (scan re-zeroes counts for fill) + msum zero ---
    zero_kernel<<<(ZN + 255) / 256, 256, 0, stream>>>(counts, ZN);
    count_kernel<<<(ET + 255) / 256, 256, 0, stream>>>(ei, counts);
    scan_kernel<<<1, 1024, 0, stream>>>(counts, row_ptr);
    fill_kernel<<<(ET + 255) / 256, 256, 0, stream>>>(ei, row_ptr, counts, col);

    // --- weight transposes + att fold, one launch ---
    prep_kernel<<<dim3(64, 64, 4), 256, 0, stream>>>(W1, W2, W3, a1s, a1d,
                                                     W1t, W2t, W3t, w_es, w_ed);

    // --- embed + layer-1 logits fused ---
    gemm0es_kernel<<<N_NODES, 128, 0, stream>>>(x, W0, b0, w_es, w_ed, h0, es, ed);

    dim3 g12(2048 / 128, (N_NODES + 127) / 128);   // (16, 157)
    dim3 g2a(2048 / 128, 79), g2b(2048 / 128, 78); // L2 M-split (attribution probe)
    dim3 g3(512 / 128, (N_NODES + 127) / 128);     // (4, 157)
    int aggb = (N_NODES + 3) / 4;                  // wave per dst, 4 per block

    // --- layer 1 (aggregate-then-transform) ---
    agg1_wave<<<aggb, 256, 0, stream>>>(h0, es, ed, row_ptr, col, bufB);   // bufB[:, :1024]
    gemm_mfma_h1<<<g12, 256, 0, stream>>>(bufB, W1t, b1, bufA, N_NODES);   // bufA = h1

    // --- layer 2 (GEMM split into two M-halves so top-5 reveals runner-up dispatches) ---
    gemm_mfma<<<g2a, 256, 0, stream>>>(bufA, W2t, bufB, N_NODES, 2048, 2048, 0);
    gemm_mfma<<<g2b, 256, 0, stream>>>(bufA, W2t, bufB, N_NODES, 2048, 2048, 79);
    att8_kernel<<<N_NODES, 256, 0, stream>>>(bufB, a2s, a2d, es, ed);
    agg_wave<8, 256><<<aggb, 256, 0, stream>>>(bufB, es, ed, row_ptr, col, b2, bufA);

    // --- layer 3 ---
    gemm_mfma<<<g3, 256, 0, stream>>>(bufA, W3t, bufB, N_NODES, 512, 2048, 0);
    att1_kernel<<<N_NODES, 64, 0, stream>>>(bufB, a3s, a3d, es, ed);
    agg_wave<1, 512><<<aggb, 256, 0, stream>>>(bufB, es, ed, row_ptr, col, b3, bufA);

    // --- pool + final (parallel pool: 157 blocks; final: 16 blocks) ---
    pool_kernel<<<(N_NODES + 127) / 128, 256, 0, stream>>>(bufA, bat, msum);
    final_kernel<<<G_GRAPHS, 256, 0, stream>>>(msum, bat, Wf, bf, out);
}

// Round 12
// 712.804 us; speedup vs baseline: 1.4515x; 1.0175x over previous
//
#include <hip/hip_runtime.h>
#include <hip/hip_bf16.h>

#define N_NODES 20000
#define N_EDGES 100000
#define ET (N_EDGES + N_NODES)   // 120000 incl. self-loops
#define G_GRAPHS 16
#define SLOPE 0.2f

using short8  = __attribute__((ext_vector_type(8))) short;
using floatx4 = __attribute__((ext_vector_type(4))) float;

__device__ __forceinline__ float lrelu(float x) { return x > 0.f ? x : SLOPE * x; }

__device__ __forceinline__ float b2f(unsigned short u) {
    union { unsigned int i; float f; } v; v.i = ((unsigned int)u) << 16; return v.f;
}
__device__ __forceinline__ unsigned short f2b(float f) {
    union { float f; unsigned int i; } v; v.f = f;
    unsigned int i = v.i;
    return (unsigned short)((i + 0x7fffu + ((i >> 16) & 1u)) >> 16);  // RNE
}

__device__ __forceinline__ void gld16(const void* g, void* l) {
    __builtin_amdgcn_global_load_lds((const __attribute__((address_space(1))) void*)g,
                                     (__attribute__((address_space(3))) void*)l, 16, 0, 0);
}

__device__ int dev_lower_bound(const int* a, int n, int key) {
    int lo = 0, hi = n;
    while (lo < hi) { int mid = (lo + hi) >> 1; if (a[mid] < key) lo = mid + 1; else hi = mid; }
    return lo;
}

__global__ void zero_kernel(int* __restrict__ p, int n) {
    int i = blockIdx.x * blockDim.x + threadIdx.x;
    if (i < n) p[i] = 0;
}

// ---------------- CSR build (by dst) ----------------
__global__ void count_kernel(const int* __restrict__ ei, int* __restrict__ counts) {
    int e = blockIdx.x * blockDim.x + threadIdx.x;
    if (e >= ET) return;
    int dst = (e < N_EDGES) ? ei[N_EDGES + e] : (e - N_EDGES);
    atomicAdd(&counts[dst], 1);
}

// single-block scan, 1024 threads (20 serial elems/thread); re-zeroes counts for fill
__global__ __launch_bounds__(1024) void scan_kernel(int* __restrict__ counts,
                                                    int* __restrict__ row_ptr) {
    __shared__ int sums[1024];
    int t = threadIdx.x;
    const int CH = (N_NODES + 1023) / 1024;   // 20
    int base = t * CH;
    int s = 0;
    for (int i = 0; i < CH; i++) { int idx = base + i; if (idx < N_NODES) s += counts[idx]; }
    sums[t] = s;
    __syncthreads();
    for (int off = 1; off < 1024; off <<= 1) {
        int v = (t >= off) ? sums[t - off] : 0;
        __syncthreads();
        sums[t] += v;
        __syncthreads();
    }
    int run = (t == 0) ? 0 : sums[t - 1];
    for (int i = 0; i < CH; i++) {
        int idx = base + i;
        if (idx < N_NODES) {
            int c = counts[idx];
            row_ptr[idx] = run;
            run += c;
            counts[idx] = 0;
        }
    }
    if (t == 1023) row_ptr[N_NODES] = run;
}

__global__ void fill_kernel(const int* __restrict__ ei, const int* __restrict__ row_ptr,
                            int* __restrict__ fill_cnt, int* __restrict__ col) {
    int e = blockIdx.x * blockDim.x + threadIdx.x;
    if (e >= ET) return;
    int src, dst;
    if (e < N_EDGES) { src = ei[e]; dst = ei[N_EDGES + e]; }
    else             { src = dst = e - N_EDGES; }
    int pos = atomicAdd(&fill_cnt[dst], 1);
    col[row_ptr[dst] + pos] = src;
}

// ---------------- prep megakernel: 3 weight transposes (z=0..2) + wes fold (z=3) ----------
__global__ void prep_kernel(const float* __restrict__ W1, const float* __restrict__ W2,
                            const float* __restrict__ W3, const float* __restrict__ a1s,
                            const float* __restrict__ a1d, unsigned short* __restrict__ W1t,
                            unsigned short* __restrict__ W2t, unsigned short* __restrict__ W3t,
                            float* __restrict__ w_es, float* __restrict__ w_ed) {
    int z = blockIdx.z;
    if (z == 3) {   // fold a1s/a1d into W1: w_es[k][hd] = <W1[k, hd*256:...], a1s[hd]>
        if (blockIdx.x >= 8 || blockIdx.y > 0 || threadIdx.x >= 128) return;
        int hd = blockIdx.x, k = threadIdx.x;
        const float* w   = W1 + (size_t)k * 2048 + hd * 256;
        const float* as_ = a1s + hd * 256;
        const float* ad_ = a1d + hd * 256;
        float s1 = 0.f, s2 = 0.f;
        for (int c = 0; c < 256; c++) { float wv = w[c]; s1 += wv * as_[c]; s2 += wv * ad_[c]; }
        w_es[k * 8 + hd] = s1;
        w_ed[k * 8 + hd] = s2;
        return;
    }
    const float* W; unsigned short* Wt; int K, N;
    if (z == 0)      { W = W1; Wt = W1t; K = 128;  N = 2048; }
    else if (z == 1) { W = W2; Wt = W2t; K = 2048; N = 2048; }
    else             { W = W3; Wt = W3t; K = 2048; N = 512;  }
    int bn = blockIdx.x * 32, bk = blockIdx.y * 32;
    if (bn >= N || bk >= K) return;
    __shared__ float tile[32][33];
    int tx = threadIdx.x & 31, ty = threadIdx.x >> 5;
#pragma unroll
    for (int p = 0; p < 32; p += 8)
        tile[ty + p][tx] = W[(size_t)(bk + ty + p) * N + bn + tx];
    __syncthreads();
#pragma unroll
    for (int p = 0; p < 32; p += 8)
        Wt[(size_t)(bn + ty + p) * K + bk + tx] = f2b(tile[tx][ty + p]);
}

// ---------------- GEMM0 + layer-1 logits fused ----------------
__global__ void gemm0es_kernel(const float* __restrict__ x, const float* __restrict__ W0,
                               const float* __restrict__ b0, const float* __restrict__ w_es,
                               const float* __restrict__ w_ed, unsigned short* __restrict__ h0,
                               float* __restrict__ es, float* __restrict__ ed) {
    __shared__ float xr[32];
    __shared__ float red[2][16];
    int n = blockIdx.x, t = threadIdx.x;  // 128 threads = 2 waves
    if (t < 32) xr[t] = x[n * 32 + t];
    __syncthreads();
    float acc = 0.f;
#pragma unroll
    for (int k = 0; k < 32; k++) acc += xr[k] * W0[k * 128 + t];
    float h = lrelu(acc + b0[t]);
    h0[(size_t)n * 128 + t] = f2b(h);
    float p[16];
#pragma unroll
    for (int hd = 0; hd < 8; hd++) {
        p[hd]     = h * w_es[t * 8 + hd];
        p[8 + hd] = h * w_ed[t * 8 + hd];
    }
#pragma unroll
    for (int m = 1; m < 64; m <<= 1)
#pragma unroll
        for (int i = 0; i < 16; i++) p[i] += __shfl_xor(p[i], m);
    int w = t >> 6, l = t & 63;
    if (l == 0)
#pragma unroll
        for (int i = 0; i < 16; i++) red[w][i] = p[i];
    __syncthreads();
    if (t < 8)       es[n * 8 + t] = red[0][t] + red[1][t];
    else if (t < 16) ed[n * 8 + (t - 8)] = red[0][t] + red[1][t];
}

// ---------------- layer-1 aggregation over 128-dim input ----------------
__global__ __launch_bounds__(256) void agg1_wave(const unsigned short* __restrict__ h0,
                                                 const float* __restrict__ es,
                                                 const float* __restrict__ ed,
                                                 const int* __restrict__ row_ptr,
                                                 const int* __restrict__ col,
                                                 unsigned short* __restrict__ outp) {
    int wv = threadIdx.x >> 6, l = threadIdx.x & 63;
    int v = blockIdx.x * 4 + wv;
    if (v >= N_NODES) return;
    int rs = row_ptr[v], deg = row_ptr[v + 1] - rs;
    float edv[8], den[8], a0[8], a1[8];
#pragma unroll
    for (int hd = 0; hd < 8; hd++) { edv[hd] = ed[v * 8 + hd]; den[hd] = 0.f; a0[hd] = 0.f; a1[hd] = 0.f; }
    int sN = (deg > 0) ? col[rs] : 0;
    for (int e = 0; e < deg; e++) {
        int s = sN;
        if (e + 1 < deg) sN = col[rs + e + 1];
        unsigned int u = *(const unsigned int*)&h0[(size_t)s * 128 + l * 2];
        float x0 = b2f((unsigned short)(u & 0xffff)), x1 = b2f((unsigned short)(u >> 16));
#pragma unroll
        for (int hd = 0; hd < 8; hd++) {
            float a = __expf(lrelu(es[s * 8 + hd] + edv[hd]));
            den[hd] += a;
            a0[hd] += a * x0;
            a1[hd] += a * x1;
        }
    }
#pragma unroll
    for (int hd = 0; hd < 8; hd++) {
        float inv = 1.f / (den[hd] + 1e-16f);
        unsigned int o = (unsigned int)f2b(a0[hd] * inv) | ((unsigned int)f2b(a1[hd] * inv) << 16);
        *(unsigned int*)&outp[(size_t)v * 1024 + hd * 128 + l * 2] = o;
    }
}

// ---------------- MFMA GEMM, BK=64, XCD-supertile swizzle ----------------
// 1D grid, lid -> (bx, by) s.t. lids with equal (lid & 7) — which round-robin to the
// same XCD — cover the same A row-tiles across all col-blocks (A row-tile stays in
// that XCD's L2 -> shorter vmcnt drains at the barrier). by = (lid>>3)/nx*8 + (lid&7).
__global__ __launch_bounds__(256) void gemm_mfma(const unsigned short* __restrict__ A,
                                                 const unsigned short* __restrict__ Bt,
                                                 unsigned short* __restrict__ C,
                                                 int M, int N, int K, int nx, int ny) {
    int lid = blockIdx.x;
    int k8 = lid & 7, jj = lid >> 3;
    int bx = jj % nx;
    int by = (jj / nx) * 8 + k8;
    if (by >= ny) return;
    __shared__ __align__(16) unsigned short As[128][64];
    __shared__ __align__(16) unsigned short Bs[128][64];
    int t = threadIdx.x;
    int w = t >> 6, l = t & 63;
    int r0 = by * 128, c0 = bx * 128;
    int wr = (w >> 1) * 64, wc = (w & 1) * 64;
    int srow = l >> 3;                          // 0..7: staging row within 8-row group
    int gcb  = (l & 7) ^ srow;                  // swizzled global colblock (row&7 == srow)
    int m16 = l & 15, qb = l >> 4;
    floatx4 acc[4][4] = {};

    for (int k0 = 0; k0 < K; k0 += 64) {
        __syncthreads();
#pragma unroll
        for (int q = 0; q < 4; q++) {
            int row = w * 32 + q * 8 + srow;
            int ga = min(r0 + row, M - 1);
            gld16(A + (size_t)ga * K + k0 + gcb * 8, &As[w * 32 + q * 8][0]);
            gld16(Bt + (size_t)(c0 + row) * K + k0 + gcb * 8, &Bs[w * 32 + q * 8][0]);
        }
        __syncthreads();
#pragma unroll
        for (int kh = 0; kh < 2; kh++) {
            int roff = (((kh * 4 + qb) ^ (m16 & 7)) * 8);
            short8 af[4], bfr[4];
#pragma unroll
            for (int i = 0; i < 4; i++) af[i] = *(const short8*)&As[wr + i * 16 + m16][roff];
#pragma unroll
            for (int j = 0; j < 4; j++) bfr[j] = *(const short8*)&Bs[wc + j * 16 + m16][roff];
#pragma unroll
            for (int i = 0; i < 4; i++)
#pragma unroll
                for (int j = 0; j < 4; j++)
                    acc[i][j] = __builtin_amdgcn_mfma_f32_16x16x32_bf16(bfr[j], af[i], acc[i][j], 0, 0, 0);
        }
    }
    int quad = l >> 4;
#pragma unroll
    for (int i = 0; i < 4; i++) {
        int r = r0 + wr + i * 16 + m16;
        if (r < M) {
#pragma unroll
            for (int j = 0; j < 4; j++) {
                int c = c0 + wc + j * 16 + quad * 4;
                ushort4 o = make_ushort4(f2b(acc[i][j][0]), f2b(acc[i][j][1]),
                                         f2b(acc[i][j][2]), f2b(acc[i][j][3]));
                *(ushort4*)&C[(size_t)r * N + c] = o;
            }
        }
    }
}

// ---------------- layer-1 per-head GEMM (BK=64): C[M,2048] = A_head[M,128]@W1t + b1, lrelu --
__global__ __launch_bounds__(256) void gemm_mfma_h1(const unsigned short* __restrict__ A,
                                                    const unsigned short* __restrict__ Bt,
                                                    const float* __restrict__ bias,
                                                    unsigned short* __restrict__ C,
                                                    int M) {
    const int N = 2048, K = 128;
    __shared__ __align__(16) unsigned short As[128][64];
    __shared__ __align__(16) unsigned short Bs[128][64];
    int t = threadIdx.x;
    int w = t >> 6, l = t & 63;
    int r0 = blockIdx.y * 128, c0 = blockIdx.x * 128;
    int wr = (w >> 1) * 64, wc = (w & 1) * 64;
    int srow = l >> 3;
    int gcb  = (l & 7) ^ srow;
    int m16 = l & 15, qb = l >> 4;
    int aoff = (c0 >> 8) * 128;                 // head * 128
    floatx4 acc[4][4] = {};

    for (int k0 = 0; k0 < K; k0 += 64) {
        __syncthreads();
#pragma unroll
        for (int q = 0; q < 4; q++) {
            int row = w * 32 + q * 8 + srow;
            int ga = min(r0 + row, M - 1);
            gld16(A + (size_t)ga * 1024 + aoff + k0 + gcb * 8, &As[w * 32 + q * 8][0]);
            gld16(Bt + (size_t)(c0 + row) * K + k0 + gcb * 8, &Bs[w * 32 + q * 8][0]);
        }
        __syncthreads();
#pragma unroll
        for (int kh = 0; kh < 2; kh++) {
            int roff = (((kh * 4 + qb) ^ (m16 & 7)) * 8);
            short8 af[4], bfr[4];
#pragma unroll
            for (int i = 0; i < 4; i++) af[i] = *(const short8*)&As[wr + i * 16 + m16][roff];
#pragma unroll
            for (int j = 0; j < 4; j++) bfr[j] = *(const short8*)&Bs[wc + j * 16 + m16][roff];
#pragma unroll
            for (int i = 0; i < 4; i++)
#pragma unroll
                for (int j = 0; j < 4; j++)
                    acc[i][j] = __builtin_amdgcn_mfma_f32_16x16x32_bf16(bfr[j], af[i], acc[i][j], 0, 0, 0);
        }
    }
    int quad = l >> 4;
#pragma unroll
    for (int i = 0; i < 4; i++) {
        int r = r0 + wr + i * 16 + m16;
        if (r < M) {
#pragma unroll
            for (int j = 0; j < 4; j++) {
                int c = c0 + wc + j * 16 + quad * 4;
                ushort4 o = make_ushort4(f2b(lrelu(acc[i][j][0] + bias[c + 0])),
                                         f2b(lrelu(acc[i][j][1] + bias[c + 1])),
                                         f2b(lrelu(acc[i][j][2] + bias[c + 2])),
                                         f2b(lrelu(acc[i][j][3] + bias[c + 3])));
                *(ushort4*)&C[(size_t)r * N + c] = o;
            }
        }
    }
}

// ---------------- attention logits (layers 2,3) ----------------
__global__ void att8_kernel(const unsigned short* __restrict__ h, const float* __restrict__ a_s,
                            const float* __restrict__ a_d, float* __restrict__ es,
                            float* __restrict__ ed) {
    int n = blockIdx.x, t = threadIdx.x;  // 256 = 8 heads x 32 lanes
    int hd = t >> 5, l = t & 31;
    const unsigned short* hr = h + (size_t)n * 2048 + hd * 256 + l * 8;
    const float* as_ = a_s + hd * 256 + l * 8;
    const float* ad_ = a_d + hd * 256 + l * 8;
    uint4 u = *(const uint4*)hr;
    float v[8] = { b2f((unsigned short)(u.x & 0xffff)), b2f((unsigned short)(u.x >> 16)),
                   b2f((unsigned short)(u.y & 0xffff)), b2f((unsigned short)(u.y >> 16)),
                   b2f((unsigned short)(u.z & 0xffff)), b2f((unsigned short)(u.z >> 16)),
                   b2f((unsigned short)(u.w & 0xffff)), b2f((unsigned short)(u.w >> 16)) };
    float s1 = 0.f, s2 = 0.f;
#pragma unroll
    for (int j = 0; j < 8; j++) { s1 += v[j] * as_[j]; s2 += v[j] * ad_[j]; }
    for (int m = 16; m >= 1; m >>= 1) { s1 += __shfl_xor(s1, m); s2 += __shfl_xor(s2, m); }
    if (l == 0) { es[n * 8 + hd] = s1; ed[n * 8 + hd] = s2; }
}

__global__ void att1_kernel(const unsigned short* __restrict__ h, const float* __restrict__ a_s,
                            const float* __restrict__ a_d, float* __restrict__ es,
                            float* __restrict__ ed) {
    int n = blockIdx.x, l = threadIdx.x;  // 64 threads
    const unsigned short* hr = h + (size_t)n * 512 + l * 8;
    const float* as_ = a_s + l * 8;
    const float* ad_ = a_d + l * 8;
    uint4 u = *(const uint4*)hr;
    float v[8] = { b2f((unsigned short)(u.x & 0xffff)), b2f((unsigned short)(u.x >> 16)),
                   b2f((unsigned short)(u.y & 0xffff)), b2f((unsigned short)(u.y >> 16)),
                   b2f((unsigned short)(u.z & 0xffff)), b2f((unsigned short)(u.z >> 16)),
                   b2f((unsigned short)(u.w & 0xffff)), b2f((unsigned short)(u.w >> 16)) };
    float s1 = 0.f, s2 = 0.f;
#pragma unroll
    for (int j = 0; j < 8; j++) { s1 += v[j] * as_[j]; s2 += v[j] * ad_[j]; }
    for (int m = 32; m >= 1; m >>= 1) { s1 += __shfl_xor(s1, m); s2 += __shfl_xor(s2, m); }
    if (l == 0) { es[n] = s1; ed[n] = s2; }
}

// ---------------- wave-per-dst GAT aggregation, edge-unrolled x2 ----------------
template <int H, int C>
__global__ __launch_bounds__(256) void agg_wave(const unsigned short* __restrict__ hmid,
                                                const float* __restrict__ es,
                                                const float* __restrict__ ed,
                                                const int* __restrict__ row_ptr,
                                                const int* __restrict__ col,
                                                const float* __restrict__ bias,
                                                unsigned short* __restrict__ out) {
    constexpr int HC = H * C;
    constexpr int CH = HC / 512;            // uint4 chunks per lane: 4 (2048) or 1 (512)
    int wv = threadIdx.x >> 6, l = threadIdx.x & 63;
    int v = blockIdx.x * 4 + wv;
    if (v >= N_NODES) return;
    int rs = row_ptr[v], deg = row_ptr[v + 1] - rs;
    int hd[CH];
    float edv[CH], den[CH], acc[CH][8];
#pragma unroll
    for (int c = 0; c < CH; c++) {
        hd[c] = (c * 512 + l * 8) / C;
        edv[c] = ed[v * H + hd[c]];
        den[c] = 0.f;
#pragma unroll
        for (int k = 0; k < 8; k++) acc[c][k] = 0.f;
    }
    int e = 0;
    for (; e + 2 <= deg; e += 2) {          // two independent gather chains in flight
        int s0 = col[rs + e], s1 = col[rs + e + 1];
        const unsigned short* hr0 = hmid + (size_t)s0 * HC + l * 8;
        const unsigned short* hr1 = hmid + (size_t)s1 * HC + l * 8;
        uint4 u0[CH], u1[CH];
#pragma unroll
        for (int c = 0; c < CH; c++) { u0[c] = *(const uint4*)(hr0 + c * 512); u1[c] = *(const uint4*)(hr1 + c * 512); }
        float ex0[CH], ex1[CH];
#pragma unroll
        for (int c = 0; c < CH; c++) {
            ex0[c] = __expf(lrelu(es[s0 * H + hd[c]] + edv[c]));
            ex1[c] = __expf(lrelu(es[s1 * H + hd[c]] + edv[c]));
            den[c] += ex0[c] + ex1[c];
        }
#pragma unroll
        for (int c = 0; c < CH; c++) {
            float a = ex0[c], b = ex1[c];
            acc[c][0] += a * b2f((unsigned short)(u0[c].x & 0xffff)) + b * b2f((unsigned short)(u1[c].x & 0xffff));
            acc[c][1] += a * b2f((unsigned short)(u0[c].x >> 16))    + b * b2f((unsigned short)(u1[c].x >> 16));
            acc[c][2] += a * b2f((unsigned short)(u0[c].y & 0xffff)) + b * b2f((unsigned short)(u1[c].y & 0xffff));
            acc[c][3] += a * b2f((unsigned short)(u0[c].y >> 16))    + b * b2f((unsigned short)(u1[c].y >> 16));
            acc[c][4] += a * b2f((unsigned short)(u0[c].z & 0xffff)) + b * b2f((unsigned short)(u1[c].z & 0xffff));
            acc[c][5] += a * b2f((unsigned short)(u0[c].z >> 16))    + b * b2f((unsigned short)(u1[c].z >> 16));
            acc[c][6] += a * b2f((unsigned short)(u0[c].w & 0xffff)) + b * b2f((unsigned short)(u1[c].w & 0xffff));
            acc[c][7] += a * b2f((unsigned short)(u0[c].w >> 16))    + b * b2f((unsigned short)(u1[c].w >> 16));
        }
    }
    if (e < deg) {
        int s = col[rs + e];
        const unsigned short* hr = hmid + (size_t)s * HC + l * 8;
#pragma unroll
        for (int c = 0; c < CH; c++) {
            uint4 u = *(const uint4*)(hr + c * 512);
            float a = __expf(lrelu(es[s * H + hd[c]] + edv[c]));
            den[c] += a;
            acc[c][0] += a * b2f((unsigned short)(u.x & 0xffff));
            acc[c][1] += a * b2f((unsigned short)(u.x >> 16));
            acc[c][2] += a * b2f((unsigned short)(u.y & 0xffff));
            acc[c][3] += a * b2f((unsigned short)(u.y >> 16));
            acc[c][4] += a * b2f((unsigned short)(u.z & 0xffff));
            acc[c][5] += a * b2f((unsigned short)(u.z >> 16));
            acc[c][6] += a * b2f((unsigned short)(u.w & 0xffff));
            acc[c][7] += a * b2f((unsigned short)(u.w >> 16));
        }
    }
#pragma unroll
    for (int c = 0; c < CH; c++) {
        float inv = 1.f / (den[c] + 1e-16f);
        unsigned short o[8];
#pragma unroll
        for (int k = 0; k < 8; k++)
            o[k] = f2b(lrelu(acc[c][k] * inv + bias[c * 512 + l * 8 + k]));
        *(uint4*)&out[(size_t)v * HC + c * 512 + l * 8] = *(const uint4*)o;
    }
}

// ---------------- mean pool (chunked partial sums + atomics; 157 blocks) ----------------
__global__ void pool_kernel(const unsigned short* __restrict__ h3, const int* __restrict__ batch,
                            float* __restrict__ msum) {
    int b0 = blockIdx.x * 128, t = threadIdx.x;  // 256 thr, 2 cols each
    int nend = min(b0 + 128, N_NODES);
    int curg = batch[b0];
    float s0 = 0.f, s1 = 0.f;
    for (int n = b0; n < nend; n++) {
        int g = batch[n];
        if (g != curg) {
            atomicAdd(&msum[curg * 512 + t * 2], s0);
            atomicAdd(&msum[curg * 512 + t * 2 + 1], s1);
            s0 = s1 = 0.f; curg = g;
        }
        unsigned int u = *(const unsigned int*)&h3[(size_t)n * 512 + t * 2];
        s0 += b2f((unsigned short)(u & 0xffff));
        s1 += b2f((unsigned short)(u >> 16));
    }
    atomicAdd(&msum[curg * 512 + t * 2], s0);
    atomicAdd(&msum[curg * 512 + t * 2 + 1], s1);
}

// ---------------- final: mean[16,512]@Wf[512,512]+bf, leaky ----------------
__global__ void final_kernel(const float* __restrict__ msum, const int* __restrict__ batch,
                             const float* __restrict__ Wf, const float* __restrict__ bf,
                             float* __restrict__ out) {
    int g = blockIdx.x, t = threadIdx.x;  // 256 threads
    __shared__ float mr[512];
    __shared__ float sinv;
    if (t == 0) {
        int st = dev_lower_bound(batch, N_NODES, g);
        int en = dev_lower_bound(batch, N_NODES, g + 1);
        sinv = 1.f / fmaxf((float)(en - st), 1.f);
    }
    __syncthreads();
    for (int c = t; c < 512; c += 256) mr[c] = msum[g * 512 + c] * sinv;
    __syncthreads();
    for (int j = t; j < 512; j += 256) {
        float s = 0.f;
        for (int k = 0; k < 512; k++) s += mr[k] * Wf[k * 512 + j];
        out[g * 512 + j] = lrelu(s + bf[j]);
    }
}

extern "C" void kernel_launch(void* const* d_in, const int* in_sizes, int n_in,
                              void* d_out, int out_size, void* d_ws, size_t ws_size,
                              hipStream_t stream) {
    const float* x   = (const float*)d_in[0];
    const int*   ei  = (const int*)d_in[1];
    const int*   bat = (const int*)d_in[2];
    const float* W0  = (const float*)d_in[3];
    const float* b0  = (const float*)d_in[4];
    const float* W1  = (const float*)d_in[5];
    const float* a1s = (const float*)d_in[6];
    const float* a1d = (const float*)d_in[7];
    const float* b1  = (const float*)d_in[8];
    const float* W2  = (const float*)d_in[9];
    const float* a2s = (const float*)d_in[10];
    const float* a2d = (const float*)d_in[11];
    const float* b2  = (const float*)d_in[12];
    const float* W3  = (const float*)d_in[13];
    const float* a3s = (const float*)d_in[14];
    const float* a3d = (const float*)d_in[15];
    const float* b3  = (const float*)d_in[16];
    const float* Wf  = (const float*)d_in[17];
    const float* bf  = (const float*)d_in[18];
    float* out = (float*)d_out;

    // workspace layout (~184 MB)
    char* p = (char*)d_ws;
    unsigned short* bufA = (unsigned short*)p; p += (size_t)N_NODES * 2048 * 2;
    unsigned short* bufB = (unsigned short*)p; p += (size_t)N_NODES * 2048 * 2;
    unsigned short* h0   = (unsigned short*)p; p += (size_t)N_NODES * 128 * 2;
    unsigned short* W1t  = (unsigned short*)p; p += (size_t)2048 * 128 * 2;
    unsigned short* W2t  = (unsigned short*)p; p += (size_t)2048 * 2048 * 2;
    unsigned short* W3t  = (unsigned short*)p; p += (size_t)512 * 2048 * 2;
    float* es   = (float*)p; p += (size_t)N_NODES * 8 * 4;
    float* ed   = (float*)p; p += (size_t)N_NODES * 8 * 4;
    float* w_es = (float*)p; p += 128 * 8 * 4;
    float* w_ed = (float*)p; p += 128 * 8 * 4;
    // counts + msum contiguous -> one zero launch covers both
    int* counts  = (int*)p; p += (size_t)N_NODES * 4;
    float* msum  = (float*)p; p += 16 * 512 * 4;
    int* row_ptr = (int*)p; p += (size_t)(N_NODES + 1) * 4;
    int* col     = (int*)p; p += (size_t)ET * 4;
    const int ZN = N_NODES + 16 * 512;   // counts + msum, in 4B words

    // --- CSR by dst (scan re-zeroes counts for fill) + msum zero ---
    zero_kernel<<<(ZN + 255) / 256, 256, 0, stream>>>(counts, ZN);
    count_kernel<<<(ET + 255) / 256, 256, 0, stream>>>(ei, counts);
    scan_kernel<<<1, 1024, 0, stream>>>(counts, row_ptr);
    fill_kernel<<<(ET + 255) / 256, 256, 0, stream>>>(ei, row_ptr, counts, col);

    // --- weight transposes + att fold, one launch ---
    prep_kernel<<<dim3(64, 64, 4), 256, 0, stream>>>(W1, W2, W3, a1s, a1d,
                                                     W1t, W2t, W3t, w_es, w_ed);

    // --- embed + layer-1 logits fused ---
    gemm0es_kernel<<<N_NODES, 128, 0, stream>>>(x, W0, b0, w_es, w_ed, h0, es, ed);

    const int NY = (N_NODES + 127) / 128;          // 157 row tiles
    const int NYP = ((NY + 7) / 8) * 8;            // padded to 160 for XCD swizzle
    dim3 g12(2048 / 128, NY);                      // h1 gemm (2D, unswizzled)
    int g2 = 16 * NYP;                             // L2 gemm 1D swizzled grid
    int g3 = 4 * NYP;                              // L3 gemm 1D swizzled grid
    int aggb = (N_NODES + 3) / 4;                  // wave per dst, 4 per block

    // --- layer 1 (aggregate-then-transform) ---
    agg1_wave<<<aggb, 256, 0, stream>>>(h0, es, ed, row_ptr, col, bufB);   // bufB[:, :1024]
    gemm_mfma_h1<<<g12, 256, 0, stream>>>(bufB, W1t, b1, bufA, N_NODES);   // bufA = h1

    // --- layer 2 ---
    gemm_mfma<<<g2, 256, 0, stream>>>(bufA, W2t, bufB, N_NODES, 2048, 2048, 16, NY);
    att8_kernel<<<N_NODES, 256, 0, stream>>>(bufB, a2s, a2d, es, ed);
    agg_wave<8, 256><<<aggb, 256, 0, stream>>>(bufB, es, ed, row_ptr, col, b2, bufA);

    // --- layer 3 ---
    gemm_mfma<<<g3, 256, 0, stream>>>(bufA, W3t, bufB, N_NODES, 512, 2048, 4, NY);
    att1_kernel<<<N_NODES, 64, 0, stream>>>(bufB, a3s, a3d, es, ed);
    agg_wave<1, 512><<<aggb, 256, 0, stream>>>(bufB, es, ed, row_ptr, col, b3, bufA);

    // --- pool + final (parallel pool: 157 blocks; final: 16 blocks) ---
    pool_kernel<<<(N_NODES + 127) / 128, 256, 0, stream>>>(bufA, bat, msum);
    final_kernel<<<G_GRAPHS, 256, 0, stream>>>(msum, bat, Wf, bf, out);
}